// Round 1
// baseline (1224.169 us; speedup 1.0000x reference)
//
#include <hip/hip_runtime.h>
#include <hip/hip_bf16.h>

#define H_DIM 1024
#define I_DIM 2752   // = 43 * 64
#define T_TOK 4096
#define NE 8

typedef __bf16 bf16;
typedef __bf16 bf16x8 __attribute__((ext_vector_type(8)));
typedef float f32x4 __attribute__((ext_vector_type(4)));

// ---- workspace layout (bytes) ----
#define WS_CNT  0                               // 16 ints
#define WS_OFFS 64                              // 16 ints
#define WS_COMB 256                             // T*NE fp32 = 128 KB
#define WS_LIST (WS_COMB + T_TOK * NE * 4)      // NE*T ints = 128 KB
#define WS_H    (WS_LIST + NE * T_TOK * 4)      // 12288 * 2752 bf16 ~ 64.5 MB
#define NROWS   (3 * T_TOK)                     // 8192 routed pairs + 4096 shared

// ---------------- gating ----------------
__global__ void gate_kernel(const float* __restrict__ x, const float* __restrict__ gw,
                            float* __restrict__ comb, int* __restrict__ cnt,
                            int* __restrict__ list) {
    int t = blockIdx.x;
    int lane = threadIdx.x;           // 0..63
    int e = lane >> 3, sub = lane & 7;
    const float* xr = x + (size_t)t * H_DIM;
    const float* wr = gw + (size_t)e * H_DIM;
    float p = 0.f;
    for (int k = sub; k < H_DIM; k += 8) p += xr[k] * wr[k];
    for (int o = 1; o < 8; o <<= 1) p += __shfl_xor(p, o);
    // lane e*8 holds logit for expert e; broadcast all 8 to every lane
    float logit[NE];
    for (int j = 0; j < NE; ++j) logit[j] = __shfl(p, j * 8);
    if (lane == 0) {
        float m = logit[0];
        for (int j = 1; j < NE; ++j) m = fmaxf(m, logit[j]);
        float s[NE], Z = 0.f;
        for (int j = 0; j < NE; ++j) { s[j] = expf(logit[j] - m); Z += s[j]; }
        for (int j = 0; j < NE; ++j) s[j] /= Z;
        int i0 = 0;
        for (int j = 1; j < NE; ++j) if (s[j] > s[i0]) i0 = j;
        int i1 = (i0 == 0) ? 1 : 0;
        for (int j = 0; j < NE; ++j) if (j != i0 && s[j] > s[i1]) i1 = j;
        float d = s[i0] + s[i1] + 1e-20f;
        float w0 = s[i0] / d, w1 = s[i1] / d;
        for (int j = 0; j < NE; ++j) comb[t * NE + j] = 0.f;
        comb[t * NE + i0] = w0;
        comb[t * NE + i1] = w1;
        int p0 = atomicAdd(&cnt[i0], 1); list[i0 * T_TOK + p0] = t;
        int p1 = atomicAdd(&cnt[i1], 1); list[i1 * T_TOK + p1] = t;
    }
}

__global__ void offs_kernel(const int* __restrict__ cnt, int* __restrict__ offs) {
    if (threadIdx.x == 0) {
        int a = 0;
        for (int e = 0; e < NE; ++e) { offs[e] = a; a += cnt[e]; }
        offs[NE] = a;   // == 8192; shared-expert rows start here
    }
}

// map linear m-tile index -> (expert, mtile, count). expert NE == shared.
__device__ inline bool map_tile(const int* cnt, int mt, int bm,
                                int& expert, int& mtile, int& count) {
    for (int e = 0; e <= NE; ++e) {
        int c = (e < NE) ? cnt[e] : T_TOK;
        int tiles = (c + bm - 1) / bm;
        if (mt < tiles) { expert = e; mtile = mt; count = c; return true; }
        mt -= tiles;
    }
    return false;
}

// ---------------- GEMM1: h = silu(x@Wg^T) * (x@Wu^T), grouped by expert ----------------
#define BM1 128
#define BN1 64
#define BK1 64
#define NT1 (I_DIM / BN1)   // 43
#define MT_MAX 104          // <= 72 routed tiles + 32 shared tiles

__global__ __launch_bounds__(256) void ffn1_kernel(
    const float* __restrict__ x, const float* __restrict__ w_gate,
    const float* __restrict__ w_up, const float* __restrict__ wsg,
    const float* __restrict__ wsu, const int* __restrict__ cnt,
    const int* __restrict__ offs, const int* __restrict__ list,
    bf16* __restrict__ h) {
    int nt = blockIdx.x % NT1;
    int mt = blockIdx.x / NT1;
    int expert, mtile, count;
    if (!map_tile(cnt, mt, BM1, expert, mtile, count)) return;
    int rowbase = offs[expert];

    const float* wg = (expert < NE) ? (w_gate + (size_t)expert * I_DIM * H_DIM) : wsg;
    const float* wu = (expert < NE) ? (w_up + (size_t)expert * I_DIM * H_DIM) : wsu;

    __shared__ bf16 As[BM1][BK1 + 8];
    __shared__ bf16 Bg[BN1][BK1 + 8];
    __shared__ bf16 Bu[BN1][BK1 + 8];

    int tid = threadIdx.x;
    int lane = tid & 63, wid = tid >> 6;
    int wm = wid >> 1, wn = wid & 1;       // wave tile: 64 rows x 32 cols
    int lr = lane & 15, lq = lane >> 4;
    int cg = tid & 15;                     // float4 column group (16 per 64-wide row)
    int iN = nt * BN1;

    int arow_tok[8];
    for (int p2 = 0; p2 < 8; ++p2) {
        int r = (tid >> 4) + p2 * 16;
        int m = mtile * BM1 + r;
        arow_tok[p2] = (m < count) ? ((expert < NE) ? list[expert * T_TOK + m] : m) : -1;
    }

    f32x4 accg[4][2] = {};
    f32x4 accu[4][2] = {};

    for (int kt = 0; kt < H_DIM; kt += BK1) {
        for (int p2 = 0; p2 < 8; ++p2) {
            int r = (tid >> 4) + p2 * 16;
            int tok = arow_tok[p2];
            float4 v = make_float4(0.f, 0.f, 0.f, 0.f);
            if (tok >= 0) v = *(const float4*)(x + (size_t)tok * H_DIM + kt + cg * 4);
            bf16* dst = &As[r][cg * 4];
            dst[0] = (bf16)v.x; dst[1] = (bf16)v.y; dst[2] = (bf16)v.z; dst[3] = (bf16)v.w;
        }
        for (int p2 = 0; p2 < 4; ++p2) {
            int r = (tid >> 4) + p2 * 16;
            float4 vg = *(const float4*)(wg + (size_t)(iN + r) * H_DIM + kt + cg * 4);
            float4 vu = *(const float4*)(wu + (size_t)(iN + r) * H_DIM + kt + cg * 4);
            bf16* dg = &Bg[r][cg * 4];
            dg[0] = (bf16)vg.x; dg[1] = (bf16)vg.y; dg[2] = (bf16)vg.z; dg[3] = (bf16)vg.w;
            bf16* du = &Bu[r][cg * 4];
            du[0] = (bf16)vu.x; du[1] = (bf16)vu.y; du[2] = (bf16)vu.z; du[3] = (bf16)vu.w;
        }
        __syncthreads();
        for (int kk = 0; kk < BK1; kk += 32) {
            bf16x8 af[4], bgf[2], buf2[2];
            for (int mi = 0; mi < 4; ++mi)
                af[mi] = *(const bf16x8*)&As[wm * 64 + mi * 16 + lr][kk + lq * 8];
            for (int ni = 0; ni < 2; ++ni) {
                bgf[ni] = *(const bf16x8*)&Bg[wn * 32 + ni * 16 + lr][kk + lq * 8];
                buf2[ni] = *(const bf16x8*)&Bu[wn * 32 + ni * 16 + lr][kk + lq * 8];
            }
            for (int mi = 0; mi < 4; ++mi)
                for (int ni = 0; ni < 2; ++ni) {
                    accg[mi][ni] = __builtin_amdgcn_mfma_f32_16x16x32_bf16(af[mi], bgf[ni], accg[mi][ni], 0, 0, 0);
                    accu[mi][ni] = __builtin_amdgcn_mfma_f32_16x16x32_bf16(af[mi], buf2[ni], accu[mi][ni], 0, 0, 0);
                }
        }
        __syncthreads();
    }
    // epilogue: silu(g)*u -> h (bf16). D layout: row = lq*4+reg, col = lr
    for (int mi = 0; mi < 4; ++mi)
        for (int ni = 0; ni < 2; ++ni)
            for (int r2 = 0; r2 < 4; ++r2) {
                int row = wm * 64 + mi * 16 + lq * 4 + r2;
                int m = mtile * BM1 + row;
                if (m >= count) continue;
                float g = accg[mi][ni][r2], u = accu[mi][ni][r2];
                float hv = g / (1.f + expf(-g)) * u;
                int col = iN + wn * 32 + ni * 16 + lr;
                h[(size_t)(rowbase + m) * I_DIM + col] = (bf16)hv;
            }
}

// ---------------- GEMM2: out += comb_w * (h @ Wd^T), grouped by expert ----------------
#define BM2 128
#define BN2 64
#define BK2 64
#define NT2 (H_DIM / BN2)   // 16

__global__ __launch_bounds__(256) void ffn2_kernel(
    const bf16* __restrict__ h, const float* __restrict__ w_down,
    const float* __restrict__ wsd, const int* __restrict__ cnt,
    const int* __restrict__ offs, const int* __restrict__ list,
    const float* __restrict__ comb, float* __restrict__ out) {
    int nt = blockIdx.x % NT2;
    int mt = blockIdx.x / NT2;
    int expert, mtile, count;
    if (!map_tile(cnt, mt, BM2, expert, mtile, count)) return;
    int rowbase = offs[expert];

    const float* wd = (expert < NE) ? (w_down + (size_t)expert * H_DIM * I_DIM) : wsd;

    __shared__ bf16 As[BM2][BK2 + 8];
    __shared__ bf16 Bs[BN2][BK2 + 8];

    int tid = threadIdx.x;
    int lane = tid & 63, wid = tid >> 6;
    int wm = wid >> 1, wn = wid & 1;
    int lr = lane & 15, lq = lane >> 4;
    int hN = nt * BN2;

    // A staging rows: r = (tid>>3) + p*32, valid cached
    int arow_m[4];
    for (int p2 = 0; p2 < 4; ++p2) {
        int r = (tid >> 3) + p2 * 32;
        int m = mtile * BM2 + r;
        arow_m[p2] = (m < count) ? m : -1;
    }

    f32x4 acc[4][2] = {};

    for (int kt = 0; kt < I_DIM; kt += BK2) {
        for (int p2 = 0; p2 < 4; ++p2) {
            int r = (tid >> 3) + p2 * 32;
            int m = arow_m[p2];
            float4 v = make_float4(0.f, 0.f, 0.f, 0.f);
            if (m >= 0) v = *(const float4*)(h + (size_t)(rowbase + m) * I_DIM + kt + (tid & 7) * 8);
            *(float4*)&As[r][(tid & 7) * 8] = v;   // raw bf16 bit copy (8 bf16)
        }
        for (int p2 = 0; p2 < 4; ++p2) {
            int r = (tid >> 4) + p2 * 16;
            float4 v = *(const float4*)(wd + (size_t)(hN + r) * I_DIM + kt + (tid & 15) * 4);
            bf16* d = &Bs[r][(tid & 15) * 4];
            d[0] = (bf16)v.x; d[1] = (bf16)v.y; d[2] = (bf16)v.z; d[3] = (bf16)v.w;
        }
        __syncthreads();
        for (int kk = 0; kk < BK2; kk += 32) {
            bf16x8 af[4], bf2[2];
            for (int mi = 0; mi < 4; ++mi)
                af[mi] = *(const bf16x8*)&As[wm * 64 + mi * 16 + lr][kk + lq * 8];
            for (int ni = 0; ni < 2; ++ni)
                bf2[ni] = *(const bf16x8*)&Bs[wn * 32 + ni * 16 + lr][kk + lq * 8];
            for (int mi = 0; mi < 4; ++mi)
                for (int ni = 0; ni < 2; ++ni)
                    acc[mi][ni] = __builtin_amdgcn_mfma_f32_16x16x32_bf16(af[mi], bf2[ni], acc[mi][ni], 0, 0, 0);
        }
        __syncthreads();
    }
    for (int mi = 0; mi < 4; ++mi)
        for (int ni = 0; ni < 2; ++ni)
            for (int r2 = 0; r2 < 4; ++r2) {
                int row = wm * 64 + mi * 16 + lq * 4 + r2;
                int m = mtile * BM2 + row;
                if (m >= count) continue;
                int tok; float wgt;
                if (expert < NE) {
                    tok = list[expert * T_TOK + m];
                    wgt = comb[tok * NE + expert];
                } else {
                    tok = m;
                    wgt = 1.f;
                }
                int col = hN + wn * 32 + ni * 16 + lr;
                atomicAdd(&out[(size_t)tok * H_DIM + col], wgt * acc[mi][ni][r2]);
            }
}

extern "C" void kernel_launch(void* const* d_in, const int* in_sizes, int n_in,
                              void* d_out, int out_size, void* d_ws, size_t ws_size,
                              hipStream_t stream) {
    (void)in_sizes; (void)n_in; (void)out_size; (void)ws_size;
    const float* x      = (const float*)d_in[0];
    const float* gate_w = (const float*)d_in[1];
    const float* w_gate = (const float*)d_in[2];
    const float* w_up   = (const float*)d_in[3];
    const float* w_down = (const float*)d_in[4];
    const float* wsg    = (const float*)d_in[5];
    const float* wsu    = (const float*)d_in[6];
    const float* wsd    = (const float*)d_in[7];
    float* out = (float*)d_out;
    char* ws = (char*)d_ws;
    int*   cnt  = (int*)(ws + WS_CNT);
    int*   offs = (int*)(ws + WS_OFFS);
    float* comb = (float*)(ws + WS_COMB);
    int*   list = (int*)(ws + WS_LIST);
    bf16*  h    = (bf16*)(ws + WS_H);

    hipMemsetAsync(cnt, 0, 64, stream);
    hipMemsetAsync(out, 0, (size_t)T_TOK * H_DIM * sizeof(float), stream);
    gate_kernel<<<T_TOK, 64, 0, stream>>>(x, gate_w, comb, cnt, list);
    offs_kernel<<<1, 64, 0, stream>>>(cnt, offs);
    ffn1_kernel<<<MT_MAX * NT1, 256, 0, stream>>>(x, w_gate, w_up, wsg, wsu, cnt, offs, list, h);
    ffn2_kernel<<<MT_MAX * NT2, 256, 0, stream>>>(h, w_down, wsd, cnt, offs, list, comb, out);
}

// Round 2
// 877.230 us; speedup vs baseline: 1.3955x; 1.3955x over previous
//
#include <hip/hip_runtime.h>
#include <hip/hip_bf16.h>

#define H_DIM 1024
#define I_DIM 2752   // = 43 * 64
#define T_TOK 4096
#define NE 8
#define NROWS (3 * T_TOK)   // 8192 routed pairs + 4096 shared

typedef __bf16 bf16;
typedef __bf16 bf16x8 __attribute__((ext_vector_type(8)));
typedef float f32x4 __attribute__((ext_vector_type(4)));

// ---- sizes (elements) ----
constexpr size_t N_X = (size_t)T_TOK * H_DIM;        // 4,194,304
constexpr size_t N_W = (size_t)NE * I_DIM * H_DIM;   // 22,544,384
constexpr size_t N_S = (size_t)I_DIM * H_DIM;        // 2,818,048
constexpr size_t N_H = (size_t)NROWS * I_DIM;        // 33,816,576

// ---- workspace layout (bytes) ----
constexpr size_t WS_CNT  = 0;
constexpr size_t WS_OFFS = 64;
constexpr size_t WS_COMB = 256;
constexpr size_t WS_LIST = WS_COMB + (size_t)T_TOK * NE * 4;   // 131328
constexpr size_t WS_XB   = WS_LIST + (size_t)NE * T_TOK * 4;   // 262400 (16B aligned)
constexpr size_t WS_WGB  = WS_XB  + N_X * 2;
constexpr size_t WS_WUB  = WS_WGB + N_W * 2;
constexpr size_t WS_WDB  = WS_WUB + N_W * 2;
constexpr size_t WS_WSGB = WS_WDB + N_W * 2;
constexpr size_t WS_WSUB = WS_WSGB + N_S * 2;
constexpr size_t WS_WSDB = WS_WSUB + N_S * 2;
constexpr size_t WS_HF   = WS_WSDB + N_S * 2;
constexpr size_t WS_NEED = WS_HF + N_H * 2;          // ~218 MB
// slow-path h (fallback if ws too small)
constexpr size_t WS_HS   = WS_XB;

// direct global->LDS, 16B per lane. LDS dst is wave-uniform base; HW scatters lane*16.
__device__ inline void gll16(const bf16* g, bf16* l) {
    __builtin_amdgcn_global_load_lds(
        (const __attribute__((address_space(1))) unsigned int*)g,
        (__attribute__((address_space(3))) unsigned int*)l, 16, 0, 0);
}

// ---------------- gating ----------------
__global__ void gate_kernel(const float* __restrict__ x, const float* __restrict__ gw,
                            float* __restrict__ comb, int* __restrict__ cnt,
                            int* __restrict__ list) {
    int t = blockIdx.x;
    int lane = threadIdx.x;
    int e = lane >> 3, sub = lane & 7;
    const float* xr = x + (size_t)t * H_DIM;
    const float* wr = gw + (size_t)e * H_DIM;
    float p = 0.f;
    for (int k = sub; k < H_DIM; k += 8) p += xr[k] * wr[k];
    for (int o = 1; o < 8; o <<= 1) p += __shfl_xor(p, o);
    float logit[NE];
    for (int j = 0; j < NE; ++j) logit[j] = __shfl(p, j * 8);
    if (lane == 0) {
        float m = logit[0];
        for (int j = 1; j < NE; ++j) m = fmaxf(m, logit[j]);
        float s[NE], Z = 0.f;
        for (int j = 0; j < NE; ++j) { s[j] = expf(logit[j] - m); Z += s[j]; }
        for (int j = 0; j < NE; ++j) s[j] /= Z;
        int i0 = 0;
        for (int j = 1; j < NE; ++j) if (s[j] > s[i0]) i0 = j;
        int i1 = (i0 == 0) ? 1 : 0;
        for (int j = 0; j < NE; ++j) if (j != i0 && s[j] > s[i1]) i1 = j;
        float d = s[i0] + s[i1] + 1e-20f;
        for (int j = 0; j < NE; ++j) comb[t * NE + j] = 0.f;
        comb[t * NE + i0] = s[i0] / d;
        comb[t * NE + i1] = s[i1] / d;
        int p0 = atomicAdd(&cnt[i0], 1); list[i0 * T_TOK + p0] = t;
        int p1 = atomicAdd(&cnt[i1], 1); list[i1 * T_TOK + p1] = t;
    }
}

__global__ void offs_kernel(const int* __restrict__ cnt, int* __restrict__ offs) {
    if (threadIdx.x == 0) {
        int a = 0;
        for (int e = 0; e < NE; ++e) { offs[e] = a; a += cnt[e]; }
        offs[NE] = a;
    }
}

// ---------------- fp32 -> bf16 conversion (weights + x), one fused kernel ----------------
__device__ inline void cvt8(const float* __restrict__ s, bf16* __restrict__ d) {
    float4 a = ((const float4*)s)[0];
    float4 b = ((const float4*)s)[1];
    bf16x8 v = { (bf16)a.x, (bf16)a.y, (bf16)a.z, (bf16)a.w,
                 (bf16)b.x, (bf16)b.y, (bf16)b.z, (bf16)b.w };
    *(bf16x8*)d = v;
}

__global__ void convert_kernel(const float* __restrict__ x,  const float* __restrict__ wg,
                               const float* __restrict__ wu, const float* __restrict__ wd,
                               const float* __restrict__ wsg, const float* __restrict__ wsu,
                               const float* __restrict__ wsd,
                               bf16* xb, bf16* wgb, bf16* wub, bf16* wdb,
                               bf16* wsgb, bf16* wsub, bf16* wsdb) {
    size_t i = ((size_t)blockIdx.x * 256 + threadIdx.x) * 8;
    if (i < N_X) { cvt8(x + i, xb + i); return; }
    i -= N_X;
    if (i < N_W) { cvt8(wg + i, wgb + i); return; }
    i -= N_W;
    if (i < N_W) { cvt8(wu + i, wub + i); return; }
    i -= N_W;
    if (i < N_W) { cvt8(wd + i, wdb + i); return; }
    i -= N_W;
    if (i < N_S) { cvt8(wsg + i, wsgb + i); return; }
    i -= N_S;
    if (i < N_S) { cvt8(wsu + i, wsub + i); return; }
    i -= N_S;
    if (i < N_S) { cvt8(wsd + i, wsdb + i); }
}

// map linear m-tile index -> (expert, mtile, count). expert NE == shared.
__device__ inline bool map_tile(const int* cnt, int mt, int bm,
                                int& expert, int& mtile, int& count) {
    for (int e = 0; e <= NE; ++e) {
        int c = (e < NE) ? cnt[e] : T_TOK;
        int tiles = (c + bm - 1) / bm;
        if (mt < tiles) { expert = e; mtile = mt; count = c; return true; }
        mt -= tiles;
    }
    return false;
}

#define BM 128
#define BK 64
#define MT_MAX 104

// ---------------- fast GEMM1: h = silu(x@Wg^T) * (x@Wu^T) ----------------
#define BN1 64
#define NT1 (I_DIM / BN1)   // 43

__global__ __launch_bounds__(256) void ffn1_fast(
    const bf16* __restrict__ xb, const bf16* __restrict__ wgb,
    const bf16* __restrict__ wub, const bf16* __restrict__ wsgb,
    const bf16* __restrict__ wsub, const int* __restrict__ cnt,
    const int* __restrict__ offs, const int* __restrict__ list,
    bf16* __restrict__ h) {
    int nt = blockIdx.x % NT1;
    int mt = blockIdx.x / NT1;
    int expert, mtile, count;
    if (!map_tile(cnt, mt, BM, expert, mtile, count)) return;
    int rowbase = offs[expert];
    const bf16* wg = (expert < NE) ? (wgb + (size_t)expert * N_S) : wsgb;
    const bf16* wu = (expert < NE) ? (wub + (size_t)expert * N_S) : wsub;

    __shared__ bf16 As[BM][BK];    // 16 KB, no padding (global_load_lds)
    __shared__ bf16 Bg[BN1][BK];   // 8 KB
    __shared__ bf16 Bu[BN1][BK];   // 8 KB

    int tid = threadIdx.x;
    int lane = tid & 63, wid = tid >> 6;
    int wm = wid >> 1, wn = wid & 1;
    int lr = lane & 15, lq = lane >> 4;
    int l8 = lane >> 3, c8 = lane & 7;
    int c8s = c8 ^ l8;               // XOR-swizzled source col-group (row&7 == l8)
    int iN = nt * BN1;

    // per-wave staging source pointers (gathered token rows for A)
    const bf16* aptr[4];
    for (int q = 0; q < 4; ++q) {
        int r = wid * 32 + q * 8 + l8;
        int m = mtile * BM + r;
        int tok = 0;
        if (m < count) tok = (expert < NE) ? list[expert * T_TOK + m] : m;
        aptr[q] = xb + (size_t)tok * H_DIM + c8s * 8;
    }
    const bf16 *gptr[2], *uptr[2];
    for (int q = 0; q < 2; ++q) {
        int r = wid * 16 + q * 8 + l8;
        gptr[q] = wg + (size_t)(iN + r) * H_DIM + c8s * 8;
        uptr[q] = wu + (size_t)(iN + r) * H_DIM + c8s * 8;
    }

    const bf16* Af = &As[0][0];
    const bf16* Bgf = &Bg[0][0];
    const bf16* Buf = &Bu[0][0];

    f32x4 accg[4][2] = {};
    f32x4 accu[4][2] = {};

    for (int kt = 0; kt < H_DIM; kt += BK) {
        for (int q = 0; q < 4; ++q) gll16(aptr[q] + kt, &As[wid * 32 + q * 8][0]);
        for (int q = 0; q < 2; ++q) {
            gll16(gptr[q] + kt, &Bg[wid * 16 + q * 8][0]);
            gll16(uptr[q] + kt, &Bu[wid * 16 + q * 8][0]);
        }
        __syncthreads();
        for (int kk = 0; kk < BK; kk += 32) {
            int G = (kk >> 3) + lq;   // global k-group of this frag
            bf16x8 af[4], bg[2], bu[2];
            for (int mi = 0; mi < 4; ++mi) {
                int R = wm * 64 + mi * 16 + lr;
                af[mi] = *(const bf16x8*)(Af + R * 64 + ((G ^ (R & 7)) << 3));
            }
            for (int ni = 0; ni < 2; ++ni) {
                int R = wn * 32 + ni * 16 + lr;
                bg[ni] = *(const bf16x8*)(Bgf + R * 64 + ((G ^ (R & 7)) << 3));
                bu[ni] = *(const bf16x8*)(Buf + R * 64 + ((G ^ (R & 7)) << 3));
            }
            for (int mi = 0; mi < 4; ++mi)
                for (int ni = 0; ni < 2; ++ni) {
                    accg[mi][ni] = __builtin_amdgcn_mfma_f32_16x16x32_bf16(af[mi], bg[ni], accg[mi][ni], 0, 0, 0);
                    accu[mi][ni] = __builtin_amdgcn_mfma_f32_16x16x32_bf16(af[mi], bu[ni], accu[mi][ni], 0, 0, 0);
                }
        }
        __syncthreads();
    }
    for (int mi = 0; mi < 4; ++mi)
        for (int ni = 0; ni < 2; ++ni)
            for (int r2 = 0; r2 < 4; ++r2) {
                int row = wm * 64 + mi * 16 + lq * 4 + r2;
                int m = mtile * BM + row;
                if (m >= count) continue;
                float g = accg[mi][ni][r2], u = accu[mi][ni][r2];
                float hv = g / (1.f + expf(-g)) * u;
                int col = iN + wn * 32 + ni * 16 + lr;
                h[(size_t)(rowbase + m) * I_DIM + col] = (bf16)hv;
            }
}

// ---------------- fast GEMM2: out += comb_w * (h @ Wd^T), 128x128 tile ----------------
#define BN2 128
#define NT2 (H_DIM / BN2)   // 8

__global__ __launch_bounds__(256) void ffn2_fast(
    const bf16* __restrict__ h, const bf16* __restrict__ wdb,
    const bf16* __restrict__ wsdb, const int* __restrict__ cnt,
    const int* __restrict__ offs, const int* __restrict__ list,
    const float* __restrict__ comb, float* __restrict__ out) {
    int nt = blockIdx.x % NT2;
    int mt = blockIdx.x / NT2;
    int expert, mtile, count;
    if (!map_tile(cnt, mt, BM, expert, mtile, count)) return;
    int rowbase = offs[expert];
    const bf16* wd = (expert < NE) ? (wdb + (size_t)expert * N_S) : wsdb;

    __shared__ bf16 As[BM][BK];    // 16 KB
    __shared__ bf16 Bs[BN2][BK];   // 16 KB

    int tid = threadIdx.x;
    int lane = tid & 63, wid = tid >> 6;
    int wm = wid >> 1, wn = wid & 1;
    int lr = lane & 15, lq = lane >> 4;
    int l8 = lane >> 3, c8 = lane & 7;
    int c8s = c8 ^ l8;
    int hN = nt * BN2;

    const bf16* aptr[4];
    for (int q = 0; q < 4; ++q) {
        int r = wid * 32 + q * 8 + l8;
        int m = mtile * BM + r;
        size_t hrow = (size_t)rowbase + ((m < count) ? m : 0);
        aptr[q] = h + hrow * I_DIM + c8s * 8;
    }
    const bf16* bptr[4];
    for (int q = 0; q < 4; ++q) {
        int r = wid * 32 + q * 8 + l8;
        bptr[q] = wd + (size_t)(hN + r) * I_DIM + c8s * 8;
    }

    const bf16* Af = &As[0][0];
    const bf16* Bf = &Bs[0][0];

    f32x4 acc[4][4] = {};

    for (int kt = 0; kt < I_DIM; kt += BK) {
        for (int q = 0; q < 4; ++q) {
            gll16(aptr[q] + kt, &As[wid * 32 + q * 8][0]);
            gll16(bptr[q] + kt, &Bs[wid * 32 + q * 8][0]);
        }
        __syncthreads();
        for (int kk = 0; kk < BK; kk += 32) {
            int G = (kk >> 3) + lq;
            bf16x8 af[4], bf2[4];
            for (int mi = 0; mi < 4; ++mi) {
                int R = wm * 64 + mi * 16 + lr;
                af[mi] = *(const bf16x8*)(Af + R * 64 + ((G ^ (R & 7)) << 3));
            }
            for (int ni = 0; ni < 4; ++ni) {
                int R = wn * 64 + ni * 16 + lr;
                bf2[ni] = *(const bf16x8*)(Bf + R * 64 + ((G ^ (R & 7)) << 3));
            }
            for (int mi = 0; mi < 4; ++mi)
                for (int ni = 0; ni < 4; ++ni)
                    acc[mi][ni] = __builtin_amdgcn_mfma_f32_16x16x32_bf16(af[mi], bf2[ni], acc[mi][ni], 0, 0, 0);
        }
        __syncthreads();
    }
    for (int mi = 0; mi < 4; ++mi)
        for (int ni = 0; ni < 4; ++ni)
            for (int r2 = 0; r2 < 4; ++r2) {
                int row = wm * 64 + mi * 16 + lq * 4 + r2;
                int m = mtile * BM + row;
                if (m >= count) continue;
                int tok; float wgt;
                if (expert < NE) {
                    tok = list[expert * T_TOK + m];
                    wgt = comb[tok * NE + expert];
                } else {
                    tok = m;
                    wgt = 1.f;
                }
                int col = hN + wn * 64 + ni * 16 + lr;
                atomicAdd(&out[(size_t)tok * H_DIM + col], wgt * acc[mi][ni][r2]);
            }
}

// ================= slow fallback (round-1, fp32 staging) =================
#define SBN1 64
#define SNT1 (I_DIM / SBN1)
#define SBN2 64
#define SNT2 (H_DIM / SBN2)

__global__ __launch_bounds__(256) void ffn1_slow(
    const float* __restrict__ x, const float* __restrict__ w_gate,
    const float* __restrict__ w_up, const float* __restrict__ wsg,
    const float* __restrict__ wsu, const int* __restrict__ cnt,
    const int* __restrict__ offs, const int* __restrict__ list,
    bf16* __restrict__ h) {
    int nt = blockIdx.x % SNT1;
    int mt = blockIdx.x / SNT1;
    int expert, mtile, count;
    if (!map_tile(cnt, mt, BM, expert, mtile, count)) return;
    int rowbase = offs[expert];
    const float* wg = (expert < NE) ? (w_gate + (size_t)expert * N_S) : wsg;
    const float* wu = (expert < NE) ? (w_up + (size_t)expert * N_S) : wsu;
    __shared__ bf16 As[BM][BK + 8];
    __shared__ bf16 Bg[SBN1][BK + 8];
    __shared__ bf16 Bu[SBN1][BK + 8];
    int tid = threadIdx.x;
    int lane = tid & 63, wid = tid >> 6;
    int wm = wid >> 1, wn = wid & 1;
    int lr = lane & 15, lq = lane >> 4;
    int cg = tid & 15;
    int iN = nt * SBN1;
    int arow_tok[8];
    for (int p2 = 0; p2 < 8; ++p2) {
        int r = (tid >> 4) + p2 * 16;
        int m = mtile * BM + r;
        arow_tok[p2] = (m < count) ? ((expert < NE) ? list[expert * T_TOK + m] : m) : -1;
    }
    f32x4 accg[4][2] = {};
    f32x4 accu[4][2] = {};
    for (int kt = 0; kt < H_DIM; kt += BK) {
        for (int p2 = 0; p2 < 8; ++p2) {
            int r = (tid >> 4) + p2 * 16;
            int tok = arow_tok[p2];
            float4 v = make_float4(0.f, 0.f, 0.f, 0.f);
            if (tok >= 0) v = *(const float4*)(x + (size_t)tok * H_DIM + kt + cg * 4);
            bf16* dst = &As[r][cg * 4];
            dst[0] = (bf16)v.x; dst[1] = (bf16)v.y; dst[2] = (bf16)v.z; dst[3] = (bf16)v.w;
        }
        for (int p2 = 0; p2 < 4; ++p2) {
            int r = (tid >> 4) + p2 * 16;
            float4 vg = *(const float4*)(wg + (size_t)(iN + r) * H_DIM + kt + cg * 4);
            float4 vu = *(const float4*)(wu + (size_t)(iN + r) * H_DIM + kt + cg * 4);
            bf16* dg = &Bg[r][cg * 4];
            dg[0] = (bf16)vg.x; dg[1] = (bf16)vg.y; dg[2] = (bf16)vg.z; dg[3] = (bf16)vg.w;
            bf16* du = &Bu[r][cg * 4];
            du[0] = (bf16)vu.x; du[1] = (bf16)vu.y; du[2] = (bf16)vu.z; du[3] = (bf16)vu.w;
        }
        __syncthreads();
        for (int kk = 0; kk < BK; kk += 32) {
            bf16x8 af[4], bgf[2], buf2[2];
            for (int mi = 0; mi < 4; ++mi)
                af[mi] = *(const bf16x8*)&As[wm * 64 + mi * 16 + lr][kk + lq * 8];
            for (int ni = 0; ni < 2; ++ni) {
                bgf[ni] = *(const bf16x8*)&Bg[wn * 32 + ni * 16 + lr][kk + lq * 8];
                buf2[ni] = *(const bf16x8*)&Bu[wn * 32 + ni * 16 + lr][kk + lq * 8];
            }
            for (int mi = 0; mi < 4; ++mi)
                for (int ni = 0; ni < 2; ++ni) {
                    accg[mi][ni] = __builtin_amdgcn_mfma_f32_16x16x32_bf16(af[mi], bgf[ni], accg[mi][ni], 0, 0, 0);
                    accu[mi][ni] = __builtin_amdgcn_mfma_f32_16x16x32_bf16(af[mi], buf2[ni], accu[mi][ni], 0, 0, 0);
                }
        }
        __syncthreads();
    }
    for (int mi = 0; mi < 4; ++mi)
        for (int ni = 0; ni < 2; ++ni)
            for (int r2 = 0; r2 < 4; ++r2) {
                int row = wm * 64 + mi * 16 + lq * 4 + r2;
                int m = mtile * BM + row;
                if (m >= count) continue;
                float g = accg[mi][ni][r2], u = accu[mi][ni][r2];
                float hv = g / (1.f + expf(-g)) * u;
                int col = iN + wn * 32 + ni * 16 + lr;
                h[(size_t)(rowbase + m) * I_DIM + col] = (bf16)hv;
            }
}

__global__ __launch_bounds__(256) void ffn2_slow(
    const bf16* __restrict__ h, const float* __restrict__ w_down,
    const float* __restrict__ wsd, const int* __restrict__ cnt,
    const int* __restrict__ offs, const int* __restrict__ list,
    const float* __restrict__ comb, float* __restrict__ out) {
    int nt = blockIdx.x % SNT2;
    int mt = blockIdx.x / SNT2;
    int expert, mtile, count;
    if (!map_tile(cnt, mt, BM, expert, mtile, count)) return;
    int rowbase = offs[expert];
    const float* wd = (expert < NE) ? (w_down + (size_t)expert * N_S) : wsd;
    __shared__ bf16 As[BM][BK + 8];
    __shared__ bf16 Bs[SBN2][BK + 8];
    int tid = threadIdx.x;
    int lane = tid & 63, wid = tid >> 6;
    int wm = wid >> 1, wn = wid & 1;
    int lr = lane & 15, lq = lane >> 4;
    int hN = nt * SBN2;
    int arow_m[4];
    for (int p2 = 0; p2 < 4; ++p2) {
        int r = (tid >> 3) + p2 * 32;
        int m = mtile * BM + r;
        arow_m[p2] = (m < count) ? m : -1;
    }
    f32x4 acc[4][2] = {};
    for (int kt = 0; kt < I_DIM; kt += BK) {
        for (int p2 = 0; p2 < 4; ++p2) {
            int r = (tid >> 3) + p2 * 32;
            int m = arow_m[p2];
            float4 v = make_float4(0.f, 0.f, 0.f, 0.f);
            if (m >= 0) v = *(const float4*)(h + (size_t)(rowbase + m) * I_DIM + kt + (tid & 7) * 8);
            *(float4*)&As[r][(tid & 7) * 8] = v;
        }
        for (int p2 = 0; p2 < 4; ++p2) {
            int r = (tid >> 4) + p2 * 16;
            float4 v = *(const float4*)(wd + (size_t)(hN + r) * I_DIM + kt + (tid & 15) * 4);
            bf16* d = &Bs[r][(tid & 15) * 4];
            d[0] = (bf16)v.x; d[1] = (bf16)v.y; d[2] = (bf16)v.z; d[3] = (bf16)v.w;
        }
        __syncthreads();
        for (int kk = 0; kk < BK; kk += 32) {
            bf16x8 af[4], bf2[2];
            for (int mi = 0; mi < 4; ++mi)
                af[mi] = *(const bf16x8*)&As[wm * 64 + mi * 16 + lr][kk + lq * 8];
            for (int ni = 0; ni < 2; ++ni)
                bf2[ni] = *(const bf16x8*)&Bs[wn * 32 + ni * 16 + lr][kk + lq * 8];
            for (int mi = 0; mi < 4; ++mi)
                for (int ni = 0; ni < 2; ++ni)
                    acc[mi][ni] = __builtin_amdgcn_mfma_f32_16x16x32_bf16(af[mi], bf2[ni], acc[mi][ni], 0, 0, 0);
        }
        __syncthreads();
    }
    for (int mi = 0; mi < 4; ++mi)
        for (int ni = 0; ni < 2; ++ni)
            for (int r2 = 0; r2 < 4; ++r2) {
                int row = wm * 64 + mi * 16 + lq * 4 + r2;
                int m = mtile * BM + row;
                if (m >= count) continue;
                int tok; float wgt;
                if (expert < NE) {
                    tok = list[expert * T_TOK + m];
                    wgt = comb[tok * NE + expert];
                } else {
                    tok = m;
                    wgt = 1.f;
                }
                int col = hN + wn * 32 + ni * 16 + lr;
                atomicAdd(&out[(size_t)tok * H_DIM + col], wgt * acc[mi][ni][r2]);
            }
}

extern "C" void kernel_launch(void* const* d_in, const int* in_sizes, int n_in,
                              void* d_out, int out_size, void* d_ws, size_t ws_size,
                              hipStream_t stream) {
    (void)in_sizes; (void)n_in; (void)out_size;
    const float* x      = (const float*)d_in[0];
    const float* gate_w = (const float*)d_in[1];
    const float* w_gate = (const float*)d_in[2];
    const float* w_up   = (const float*)d_in[3];
    const float* w_down = (const float*)d_in[4];
    const float* wsg    = (const float*)d_in[5];
    const float* wsu    = (const float*)d_in[6];
    const float* wsd    = (const float*)d_in[7];
    float* out = (float*)d_out;
    char* ws = (char*)d_ws;
    int*   cnt  = (int*)(ws + WS_CNT);
    int*   offs = (int*)(ws + WS_OFFS);
    float* comb = (float*)(ws + WS_COMB);
    int*   list = (int*)(ws + WS_LIST);

    hipMemsetAsync(cnt, 0, 64, stream);
    hipMemsetAsync(out, 0, (size_t)T_TOK * H_DIM * sizeof(float), stream);
    gate_kernel<<<T_TOK, 64, 0, stream>>>(x, gate_w, comb, cnt, list);
    offs_kernel<<<1, 64, 0, stream>>>(cnt, offs);

    if (ws_size >= WS_NEED) {
        bf16* xb   = (bf16*)(ws + WS_XB);
        bf16* wgb  = (bf16*)(ws + WS_WGB);
        bf16* wub  = (bf16*)(ws + WS_WUB);
        bf16* wdb  = (bf16*)(ws + WS_WDB);
        bf16* wsgb = (bf16*)(ws + WS_WSGB);
        bf16* wsub = (bf16*)(ws + WS_WSUB);
        bf16* wsdb = (bf16*)(ws + WS_WSDB);
        bf16* h    = (bf16*)(ws + WS_HF);
        size_t total8 = (N_X + 3 * N_W + 3 * N_S) / 8;           // 10,035,200
        int cblocks = (int)((total8 + 255) / 256);               // 39,200
        convert_kernel<<<cblocks, 256, 0, stream>>>(x, w_gate, w_up, w_down, wsg, wsu, wsd,
                                                    xb, wgb, wub, wdb, wsgb, wsub, wsdb);
        ffn1_fast<<<MT_MAX * NT1, 256, 0, stream>>>(xb, wgb, wub, wsgb, wsub, cnt, offs, list, h);
        ffn2_fast<<<MT_MAX * NT2, 256, 0, stream>>>(h, wdb, wsdb, cnt, offs, list, comb, out);
    } else {
        bf16* h = (bf16*)(ws + WS_HS);
        ffn1_slow<<<MT_MAX * SNT1, 256, 0, stream>>>(x, w_gate, w_up, wsg, wsu, cnt, offs, list, h);
        ffn2_slow<<<MT_MAX * SNT2, 256, 0, stream>>>(h, w_down, wsd, cnt, offs, list, comb, out);
    }
}

// Round 3
// 801.635 us; speedup vs baseline: 1.5271x; 1.0943x over previous
//
#include <hip/hip_runtime.h>
#include <hip/hip_bf16.h>

#define H_DIM 1024
#define I_DIM 2752   // = 43 * 64
#define T_TOK 4096
#define NE 8
#define NROWS (3 * T_TOK)   // 8192 routed pairs + 4096 shared

typedef __bf16 bf16;
typedef __bf16 bf16x8 __attribute__((ext_vector_type(8)));
typedef __bf16 bf16x4 __attribute__((ext_vector_type(4)));
typedef float f32x4 __attribute__((ext_vector_type(4)));

// ---- sizes (elements) ----
constexpr size_t N_X = (size_t)T_TOK * H_DIM;        // 4,194,304
constexpr size_t N_W = (size_t)NE * I_DIM * H_DIM;   // 22,544,384
constexpr size_t N_S = (size_t)I_DIM * H_DIM;        // 2,818,048
constexpr size_t N_H = (size_t)NROWS * I_DIM;        // 33,816,576

// ---- workspace layout (bytes) ----
constexpr size_t WS_CNT  = 0;
constexpr size_t WS_OFFS = 64;
constexpr size_t WS_COMB = 256;                                  // T*NE fp32 (slow path only)
constexpr size_t WS_TOKEP = WS_COMB + (size_t)T_TOK * NE * 4;    // int4 per token
constexpr size_t WS_TOKW  = WS_TOKEP + (size_t)T_TOK * 16;       // float2 per token
constexpr size_t WS_LIST  = WS_TOKW + (size_t)T_TOK * 8;
constexpr size_t WS_XB   = WS_LIST + (size_t)NE * T_TOK * 4;
constexpr size_t WS_WGB  = WS_XB  + N_X * 2;
constexpr size_t WS_WUB  = WS_WGB + N_W * 2;
constexpr size_t WS_WDB  = WS_WUB + N_W * 2;
constexpr size_t WS_WSGB = WS_WDB + N_W * 2;
constexpr size_t WS_WSUB = WS_WSGB + N_S * 2;
constexpr size_t WS_WSDB = WS_WSUB + N_S * 2;
constexpr size_t WS_HF   = WS_WSDB + N_S * 2;
constexpr size_t WS_NEED = WS_HF + N_H * 2;          // ~218 MB
// eo[NROWS][H_DIM] bf16 (24 MB) aliases wgb (45 MB) — wgb is dead after ffn1
constexpr size_t WS_EO   = WS_WGB;
// slow-path h (fallback if ws too small)
constexpr size_t WS_HS   = WS_XB;

// direct global->LDS, 16B per lane. LDS dst is wave-uniform base; HW scatters lane*16.
__device__ inline void gll16(const bf16* g, bf16* l) {
    __builtin_amdgcn_global_load_lds(
        (const __attribute__((address_space(1))) unsigned int*)g,
        (__attribute__((address_space(3))) unsigned int*)l, 16, 0, 0);
}

// ---------------- gating ----------------
__global__ void gate_kernel(const float* __restrict__ x, const float* __restrict__ gw,
                            float* __restrict__ comb, int4* __restrict__ tok_ep,
                            float2* __restrict__ tok_w, int* __restrict__ cnt,
                            int* __restrict__ list) {
    int t = blockIdx.x;
    int lane = threadIdx.x;
    int e = lane >> 3, sub = lane & 7;
    const float* xr = x + (size_t)t * H_DIM;
    const float* wr = gw + (size_t)e * H_DIM;
    float p = 0.f;
    for (int k = sub; k < H_DIM; k += 8) p += xr[k] * wr[k];
    for (int o = 1; o < 8; o <<= 1) p += __shfl_xor(p, o);
    float logit[NE];
    for (int j = 0; j < NE; ++j) logit[j] = __shfl(p, j * 8);
    if (lane == 0) {
        float m = logit[0];
        for (int j = 1; j < NE; ++j) m = fmaxf(m, logit[j]);
        float s[NE], Z = 0.f;
        for (int j = 0; j < NE; ++j) { s[j] = expf(logit[j] - m); Z += s[j]; }
        for (int j = 0; j < NE; ++j) s[j] /= Z;
        int i0 = 0;
        for (int j = 1; j < NE; ++j) if (s[j] > s[i0]) i0 = j;
        int i1 = (i0 == 0) ? 1 : 0;
        for (int j = 0; j < NE; ++j) if (j != i0 && s[j] > s[i1]) i1 = j;
        float d = s[i0] + s[i1] + 1e-20f;
        float w0 = s[i0] / d, w1 = s[i1] / d;
        for (int j = 0; j < NE; ++j) comb[t * NE + j] = 0.f;
        comb[t * NE + i0] = w0;
        comb[t * NE + i1] = w1;
        int p0 = atomicAdd(&cnt[i0], 1); list[i0 * T_TOK + p0] = t;
        int p1 = atomicAdd(&cnt[i1], 1); list[i1 * T_TOK + p1] = t;
        tok_ep[t] = make_int4(i0, p0, i1, p1);
        tok_w[t] = make_float2(w0, w1);
    }
}

__global__ void offs_kernel(const int* __restrict__ cnt, int* __restrict__ offs) {
    if (threadIdx.x == 0) {
        int a = 0;
        for (int e = 0; e < NE; ++e) { offs[e] = a; a += cnt[e]; }
        offs[NE] = a;   // routed total; shared rows start here
    }
}

// ---------------- fp32 -> bf16 conversion ----------------
__device__ inline void cvt8(const float* __restrict__ s, bf16* __restrict__ d) {
    float4 a = ((const float4*)s)[0];
    float4 b = ((const float4*)s)[1];
    bf16x8 v = { (bf16)a.x, (bf16)a.y, (bf16)a.z, (bf16)a.w,
                 (bf16)b.x, (bf16)b.y, (bf16)b.z, (bf16)b.w };
    *(bf16x8*)d = v;
}

__global__ void convert_kernel(const float* __restrict__ x,  const float* __restrict__ wg,
                               const float* __restrict__ wu, const float* __restrict__ wd,
                               const float* __restrict__ wsg, const float* __restrict__ wsu,
                               const float* __restrict__ wsd,
                               bf16* xb, bf16* wgb, bf16* wub, bf16* wdb,
                               bf16* wsgb, bf16* wsub, bf16* wsdb) {
    size_t i = ((size_t)blockIdx.x * 256 + threadIdx.x) * 8;
    if (i < N_X) { cvt8(x + i, xb + i); return; }
    i -= N_X;
    if (i < N_W) { cvt8(wg + i, wgb + i); return; }
    i -= N_W;
    if (i < N_W) { cvt8(wu + i, wub + i); return; }
    i -= N_W;
    if (i < N_W) { cvt8(wd + i, wdb + i); return; }
    i -= N_W;
    if (i < N_S) { cvt8(wsg + i, wsgb + i); return; }
    i -= N_S;
    if (i < N_S) { cvt8(wsu + i, wsub + i); return; }
    i -= N_S;
    if (i < N_S) { cvt8(wsd + i, wsdb + i); }
}

// map linear m-tile index -> (expert, mtile, count). expert NE == shared.
__device__ inline bool map_tile(const int* cnt, int mt, int bm,
                                int& expert, int& mtile, int& count) {
    for (int e = 0; e <= NE; ++e) {
        int c = (e < NE) ? cnt[e] : T_TOK;
        int tiles = (c + bm - 1) / bm;
        if (mt < tiles) { expert = e; mtile = mt; count = c; return true; }
        mt -= tiles;
    }
    return false;
}

#define BM 128
#define BK 64
#define MT_MAX 104

// ---------------- fast GEMM1: h = silu(x@Wg^T) * (x@Wu^T) ----------------
#define BN1 64
#define NT1 (I_DIM / BN1)   // 43

__global__ __launch_bounds__(256) void ffn1_fast(
    const bf16* __restrict__ xb, const bf16* __restrict__ wgb,
    const bf16* __restrict__ wub, const bf16* __restrict__ wsgb,
    const bf16* __restrict__ wsub, const int* __restrict__ cnt,
    const int* __restrict__ offs, const int* __restrict__ list,
    bf16* __restrict__ h) {
    // mt-fastest: consecutive blocks share the same weight n-tile (L2 reuse)
    int mt = blockIdx.x % MT_MAX;
    int nt = blockIdx.x / MT_MAX;
    int expert, mtile, count;
    if (!map_tile(cnt, mt, BM, expert, mtile, count)) return;
    int rowbase = offs[expert];
    const bf16* wg = (expert < NE) ? (wgb + (size_t)expert * N_S) : wsgb;
    const bf16* wu = (expert < NE) ? (wub + (size_t)expert * N_S) : wsub;

    __shared__ bf16 As[BM][BK];
    __shared__ bf16 Bg[BN1][BK];
    __shared__ bf16 Bu[BN1][BK];

    int tid = threadIdx.x;
    int lane = tid & 63, wid = tid >> 6;
    int wm = wid >> 1, wn = wid & 1;
    int lr = lane & 15, lq = lane >> 4;
    int l8 = lane >> 3, c8 = lane & 7;
    int c8s = c8 ^ l8;               // XOR-swizzled source col-group
    int iN = nt * BN1;

    const bf16* aptr[4];
    for (int q = 0; q < 4; ++q) {
        int r = wid * 32 + q * 8 + l8;
        int m = mtile * BM + r;
        int tok = 0;
        if (m < count) tok = (expert < NE) ? list[expert * T_TOK + m] : m;
        aptr[q] = xb + (size_t)tok * H_DIM + c8s * 8;
    }
    const bf16 *gptr[2], *uptr[2];
    for (int q = 0; q < 2; ++q) {
        int r = wid * 16 + q * 8 + l8;
        gptr[q] = wg + (size_t)(iN + r) * H_DIM + c8s * 8;
        uptr[q] = wu + (size_t)(iN + r) * H_DIM + c8s * 8;
    }

    const bf16* Af = &As[0][0];
    const bf16* Bgf = &Bg[0][0];
    const bf16* Buf = &Bu[0][0];

    f32x4 accg[4][2] = {};
    f32x4 accu[4][2] = {};

    for (int kt = 0; kt < H_DIM; kt += BK) {
        for (int q = 0; q < 4; ++q) gll16(aptr[q] + kt, &As[wid * 32 + q * 8][0]);
        for (int q = 0; q < 2; ++q) {
            gll16(gptr[q] + kt, &Bg[wid * 16 + q * 8][0]);
            gll16(uptr[q] + kt, &Bu[wid * 16 + q * 8][0]);
        }
        __syncthreads();
        for (int kk = 0; kk < BK; kk += 32) {
            int G = (kk >> 3) + lq;
            bf16x8 af[4], bg[2], bu[2];
            for (int mi = 0; mi < 4; ++mi) {
                int R = wm * 64 + mi * 16 + lr;
                af[mi] = *(const bf16x8*)(Af + R * 64 + ((G ^ (R & 7)) << 3));
            }
            for (int ni = 0; ni < 2; ++ni) {
                int R = wn * 32 + ni * 16 + lr;
                bg[ni] = *(const bf16x8*)(Bgf + R * 64 + ((G ^ (R & 7)) << 3));
                bu[ni] = *(const bf16x8*)(Buf + R * 64 + ((G ^ (R & 7)) << 3));
            }
            for (int mi = 0; mi < 4; ++mi)
                for (int ni = 0; ni < 2; ++ni) {
                    accg[mi][ni] = __builtin_amdgcn_mfma_f32_16x16x32_bf16(af[mi], bg[ni], accg[mi][ni], 0, 0, 0);
                    accu[mi][ni] = __builtin_amdgcn_mfma_f32_16x16x32_bf16(af[mi], bu[ni], accu[mi][ni], 0, 0, 0);
                }
        }
        __syncthreads();
    }
    for (int mi = 0; mi < 4; ++mi)
        for (int ni = 0; ni < 2; ++ni)
            for (int r2 = 0; r2 < 4; ++r2) {
                int row = wm * 64 + mi * 16 + lq * 4 + r2;
                int m = mtile * BM + row;
                if (m >= count) continue;
                float g = accg[mi][ni][r2], u = accu[mi][ni][r2];
                float hv = g / (1.f + expf(-g)) * u;
                int col = iN + wn * 32 + ni * 16 + lr;
                h[(size_t)(rowbase + m) * I_DIM + col] = (bf16)hv;
            }
}

// ---------------- fast GEMM2: eo = h @ Wd^T (atomic-free, per-row output) ----------------
#define BN2 128
#define NT2 (H_DIM / BN2)   // 8

__global__ __launch_bounds__(256) void ffn2_fast(
    const bf16* __restrict__ h, const bf16* __restrict__ wdb,
    const bf16* __restrict__ wsdb, const int* __restrict__ cnt,
    const int* __restrict__ offs, bf16* __restrict__ eo) {
    int nt = blockIdx.x % NT2;   // nt-fastest: consecutive blocks share the h A-tile
    int mt = blockIdx.x / NT2;
    int expert, mtile, count;
    if (!map_tile(cnt, mt, BM, expert, mtile, count)) return;
    int rowbase = offs[expert];
    const bf16* wd = (expert < NE) ? (wdb + (size_t)expert * N_S) : wsdb;

    __shared__ bf16 As[BM][BK];
    __shared__ bf16 Bs[BN2][BK];

    int tid = threadIdx.x;
    int lane = tid & 63, wid = tid >> 6;
    int wm = wid >> 1, wn = wid & 1;
    int lr = lane & 15, lq = lane >> 4;
    int l8 = lane >> 3, c8 = lane & 7;
    int c8s = c8 ^ l8;
    int hN = nt * BN2;

    const bf16* aptr[4];
    for (int q = 0; q < 4; ++q) {
        int r = wid * 32 + q * 8 + l8;
        int m = mtile * BM + r;
        size_t hrow = (size_t)rowbase + ((m < count) ? m : 0);
        aptr[q] = h + hrow * I_DIM + c8s * 8;
    }
    const bf16* bptr[4];
    for (int q = 0; q < 4; ++q) {
        int r = wid * 32 + q * 8 + l8;
        bptr[q] = wd + (size_t)(hN + r) * I_DIM + c8s * 8;
    }

    const bf16* Af = &As[0][0];
    const bf16* Bf = &Bs[0][0];

    f32x4 acc[4][4] = {};

    for (int kt = 0; kt < I_DIM; kt += BK) {
        for (int q = 0; q < 4; ++q) {
            gll16(aptr[q] + kt, &As[wid * 32 + q * 8][0]);
            gll16(bptr[q] + kt, &Bs[wid * 32 + q * 8][0]);
        }
        __syncthreads();
        for (int kk = 0; kk < BK; kk += 32) {
            int G = (kk >> 3) + lq;
            bf16x8 af[4], bf2[4];
            for (int mi = 0; mi < 4; ++mi) {
                int R = wm * 64 + mi * 16 + lr;
                af[mi] = *(const bf16x8*)(Af + R * 64 + ((G ^ (R & 7)) << 3));
            }
            for (int ni = 0; ni < 4; ++ni) {
                int R = wn * 64 + ni * 16 + lr;
                bf2[ni] = *(const bf16x8*)(Bf + R * 64 + ((G ^ (R & 7)) << 3));
            }
            for (int mi = 0; mi < 4; ++mi)
                for (int ni = 0; ni < 4; ++ni)
                    acc[mi][ni] = __builtin_amdgcn_mfma_f32_16x16x32_bf16(af[mi], bf2[ni], acc[mi][ni], 0, 0, 0);
        }
        __syncthreads();
    }
    for (int mi = 0; mi < 4; ++mi)
        for (int ni = 0; ni < 4; ++ni)
            for (int r2 = 0; r2 < 4; ++r2) {
                int row = wm * 64 + mi * 16 + lq * 4 + r2;
                int m = mtile * BM + row;
                if (m >= count) continue;
                int col = hN + wn * 64 + ni * 16 + lr;
                eo[(size_t)(rowbase + m) * H_DIM + col] = (bf16)acc[mi][ni][r2];
            }
}

// ---------------- combine: out[t] = w0*eo[r0] + w1*eo[r1] + eo[shared_t] ----------------
__global__ __launch_bounds__(256) void combine_kernel(
    const bf16* __restrict__ eo, const int* __restrict__ offs,
    const int4* __restrict__ tok_ep, const float2* __restrict__ tok_w,
    float* __restrict__ out) {
    int t = blockIdx.x;
    int c = threadIdx.x * 4;
    int4 ep = tok_ep[t];
    float2 w = tok_w[t];
    size_t r0 = (size_t)(offs[ep.x] + ep.y) * H_DIM + c;
    size_t r1 = (size_t)(offs[ep.z] + ep.w) * H_DIM + c;
    size_t rs = (size_t)(offs[NE] + t) * H_DIM + c;
    bf16x4 a = *(const bf16x4*)(eo + r0);
    bf16x4 b = *(const bf16x4*)(eo + r1);
    bf16x4 s = *(const bf16x4*)(eo + rs);
    float4 o;
    o.x = w.x * (float)a[0] + w.y * (float)b[0] + (float)s[0];
    o.y = w.x * (float)a[1] + w.y * (float)b[1] + (float)s[1];
    o.z = w.x * (float)a[2] + w.y * (float)b[2] + (float)s[2];
    o.w = w.x * (float)a[3] + w.y * (float)b[3] + (float)s[3];
    *(float4*)(out + (size_t)t * H_DIM + c) = o;
}

// ================= slow fallback (round-1, fp32 staging) =================
#define SBN1 64
#define SNT1 (I_DIM / SBN1)
#define SBN2 64
#define SNT2 (H_DIM / SBN2)

__global__ __launch_bounds__(256) void ffn1_slow(
    const float* __restrict__ x, const float* __restrict__ w_gate,
    const float* __restrict__ w_up, const float* __restrict__ wsg,
    const float* __restrict__ wsu, const int* __restrict__ cnt,
    const int* __restrict__ offs, const int* __restrict__ list,
    bf16* __restrict__ h) {
    int nt = blockIdx.x % SNT1;
    int mt = blockIdx.x / SNT1;
    int expert, mtile, count;
    if (!map_tile(cnt, mt, BM, expert, mtile, count)) return;
    int rowbase = offs[expert];
    const float* wg = (expert < NE) ? (w_gate + (size_t)expert * N_S) : wsg;
    const float* wu = (expert < NE) ? (w_up + (size_t)expert * N_S) : wsu;
    __shared__ bf16 As[BM][BK + 8];
    __shared__ bf16 Bg[SBN1][BK + 8];
    __shared__ bf16 Bu[SBN1][BK + 8];
    int tid = threadIdx.x;
    int lane = tid & 63, wid = tid >> 6;
    int wm = wid >> 1, wn = wid & 1;
    int lr = lane & 15, lq = lane >> 4;
    int cg = tid & 15;
    int iN = nt * SBN1;
    int arow_tok[8];
    for (int p2 = 0; p2 < 8; ++p2) {
        int r = (tid >> 4) + p2 * 16;
        int m = mtile * BM + r;
        arow_tok[p2] = (m < count) ? ((expert < NE) ? list[expert * T_TOK + m] : m) : -1;
    }
    f32x4 accg[4][2] = {};
    f32x4 accu[4][2] = {};
    for (int kt = 0; kt < H_DIM; kt += BK) {
        for (int p2 = 0; p2 < 8; ++p2) {
            int r = (tid >> 4) + p2 * 16;
            int tok = arow_tok[p2];
            float4 v = make_float4(0.f, 0.f, 0.f, 0.f);
            if (tok >= 0) v = *(const float4*)(x + (size_t)tok * H_DIM + kt + cg * 4);
            bf16* dst = &As[r][cg * 4];
            dst[0] = (bf16)v.x; dst[1] = (bf16)v.y; dst[2] = (bf16)v.z; dst[3] = (bf16)v.w;
        }
        for (int p2 = 0; p2 < 4; ++p2) {
            int r = (tid >> 4) + p2 * 16;
            float4 vg = *(const float4*)(wg + (size_t)(iN + r) * H_DIM + kt + cg * 4);
            float4 vu = *(const float4*)(wu + (size_t)(iN + r) * H_DIM + kt + cg * 4);
            bf16* dg = &Bg[r][cg * 4];
            dg[0] = (bf16)vg.x; dg[1] = (bf16)vg.y; dg[2] = (bf16)vg.z; dg[3] = (bf16)vg.w;
            bf16* du = &Bu[r][cg * 4];
            du[0] = (bf16)vu.x; du[1] = (bf16)vu.y; du[2] = (bf16)vu.z; du[3] = (bf16)vu.w;
        }
        __syncthreads();
        for (int kk = 0; kk < BK; kk += 32) {
            bf16x8 af[4], bgf[2], buf2[2];
            for (int mi = 0; mi < 4; ++mi)
                af[mi] = *(const bf16x8*)&As[wm * 64 + mi * 16 + lr][kk + lq * 8];
            for (int ni = 0; ni < 2; ++ni) {
                bgf[ni] = *(const bf16x8*)&Bg[wn * 32 + ni * 16 + lr][kk + lq * 8];
                buf2[ni] = *(const bf16x8*)&Bu[wn * 32 + ni * 16 + lr][kk + lq * 8];
            }
            for (int mi = 0; mi < 4; ++mi)
                for (int ni = 0; ni < 2; ++ni) {
                    accg[mi][ni] = __builtin_amdgcn_mfma_f32_16x16x32_bf16(af[mi], bgf[ni], accg[mi][ni], 0, 0, 0);
                    accu[mi][ni] = __builtin_amdgcn_mfma_f32_16x16x32_bf16(af[mi], buf2[ni], accu[mi][ni], 0, 0, 0);
                }
        }
        __syncthreads();
    }
    for (int mi = 0; mi < 4; ++mi)
        for (int ni = 0; ni < 2; ++ni)
            for (int r2 = 0; r2 < 4; ++r2) {
                int row = wm * 64 + mi * 16 + lq * 4 + r2;
                int m = mtile * BM + row;
                if (m >= count) continue;
                float g = accg[mi][ni][r2], u = accu[mi][ni][r2];
                float hv = g / (1.f + expf(-g)) * u;
                int col = iN + wn * 32 + ni * 16 + lr;
                h[(size_t)(rowbase + m) * I_DIM + col] = (bf16)hv;
            }
}

__global__ __launch_bounds__(256) void ffn2_slow(
    const bf16* __restrict__ h, const float* __restrict__ w_down,
    const float* __restrict__ wsd, const int* __restrict__ cnt,
    const int* __restrict__ offs, const int* __restrict__ list,
    const float* __restrict__ comb, float* __restrict__ out) {
    int nt = blockIdx.x % SNT2;
    int mt = blockIdx.x / SNT2;
    int expert, mtile, count;
    if (!map_tile(cnt, mt, BM, expert, mtile, count)) return;
    int rowbase = offs[expert];
    const float* wd = (expert < NE) ? (w_down + (size_t)expert * N_S) : wsd;
    __shared__ bf16 As[BM][BK + 8];
    __shared__ bf16 Bs[SBN2][BK + 8];
    int tid = threadIdx.x;
    int lane = tid & 63, wid = tid >> 6;
    int wm = wid >> 1, wn = wid & 1;
    int lr = lane & 15, lq = lane >> 4;
    int hN = nt * SBN2;
    int arow_m[4];
    for (int p2 = 0; p2 < 4; ++p2) {
        int r = (tid >> 3) + p2 * 32;
        int m = mtile * BM + r;
        arow_m[p2] = (m < count) ? m : -1;
    }
    f32x4 acc[4][2] = {};
    for (int kt = 0; kt < I_DIM; kt += BK) {
        for (int p2 = 0; p2 < 4; ++p2) {
            int r = (tid >> 3) + p2 * 32;
            int m = arow_m[p2];
            float4 v = make_float4(0.f, 0.f, 0.f, 0.f);
            if (m >= 0) v = *(const float4*)(h + (size_t)(rowbase + m) * I_DIM + kt + (tid & 7) * 8);
            *(float4*)&As[r][(tid & 7) * 8] = v;
        }
        for (int p2 = 0; p2 < 4; ++p2) {
            int r = (tid >> 4) + p2 * 16;
            float4 v = *(const float4*)(wd + (size_t)(hN + r) * I_DIM + kt + (tid & 15) * 4);
            bf16* d = &Bs[r][(tid & 15) * 4];
            d[0] = (bf16)v.x; d[1] = (bf16)v.y; d[2] = (bf16)v.z; d[3] = (bf16)v.w;
        }
        __syncthreads();
        for (int kk = 0; kk < BK; kk += 32) {
            bf16x8 af[4], bf2[2];
            for (int mi = 0; mi < 4; ++mi)
                af[mi] = *(const bf16x8*)&As[wm * 64 + mi * 16 + lr][kk + lq * 8];
            for (int ni = 0; ni < 2; ++ni)
                bf2[ni] = *(const bf16x8*)&Bs[wn * 32 + ni * 16 + lr][kk + lq * 8];
            for (int mi = 0; mi < 4; ++mi)
                for (int ni = 0; ni < 2; ++ni)
                    acc[mi][ni] = __builtin_amdgcn_mfma_f32_16x16x32_bf16(af[mi], bf2[ni], acc[mi][ni], 0, 0, 0);
        }
        __syncthreads();
    }
    for (int mi = 0; mi < 4; ++mi)
        for (int ni = 0; ni < 2; ++ni)
            for (int r2 = 0; r2 < 4; ++r2) {
                int row = wm * 64 + mi * 16 + lq * 4 + r2;
                int m = mtile * BM + row;
                if (m >= count) continue;
                int tok; float wgt;
                if (expert < NE) {
                    tok = list[expert * T_TOK + m];
                    wgt = comb[tok * NE + expert];
                } else {
                    tok = m;
                    wgt = 1.f;
                }
                int col = hN + wn * 32 + ni * 16 + lr;
                atomicAdd(&out[(size_t)tok * H_DIM + col], wgt * acc[mi][ni][r2]);
            }
}

extern "C" void kernel_launch(void* const* d_in, const int* in_sizes, int n_in,
                              void* d_out, int out_size, void* d_ws, size_t ws_size,
                              hipStream_t stream) {
    (void)in_sizes; (void)n_in; (void)out_size;
    const float* x      = (const float*)d_in[0];
    const float* gate_w = (const float*)d_in[1];
    const float* w_gate = (const float*)d_in[2];
    const float* w_up   = (const float*)d_in[3];
    const float* w_down = (const float*)d_in[4];
    const float* wsg    = (const float*)d_in[5];
    const float* wsu    = (const float*)d_in[6];
    const float* wsd    = (const float*)d_in[7];
    float* out = (float*)d_out;
    char* ws = (char*)d_ws;
    int*    cnt    = (int*)(ws + WS_CNT);
    int*    offs   = (int*)(ws + WS_OFFS);
    float*  comb   = (float*)(ws + WS_COMB);
    int4*   tok_ep = (int4*)(ws + WS_TOKEP);
    float2* tok_w  = (float2*)(ws + WS_TOKW);
    int*    list   = (int*)(ws + WS_LIST);

    hipMemsetAsync(cnt, 0, 64, stream);
    gate_kernel<<<T_TOK, 64, 0, stream>>>(x, gate_w, comb, tok_ep, tok_w, cnt, list);
    offs_kernel<<<1, 64, 0, stream>>>(cnt, offs);

    if (ws_size >= WS_NEED) {
        bf16* xb   = (bf16*)(ws + WS_XB);
        bf16* wgb  = (bf16*)(ws + WS_WGB);
        bf16* wub  = (bf16*)(ws + WS_WUB);
        bf16* wdb  = (bf16*)(ws + WS_WDB);
        bf16* wsgb = (bf16*)(ws + WS_WSGB);
        bf16* wsub = (bf16*)(ws + WS_WSUB);
        bf16* wsdb = (bf16*)(ws + WS_WSDB);
        bf16* h    = (bf16*)(ws + WS_HF);
        bf16* eo   = (bf16*)(ws + WS_EO);    // aliases wgb (dead after ffn1)
        size_t total8 = (N_X + 3 * N_W + 3 * N_S) / 8;
        int cblocks = (int)((total8 + 255) / 256);
        convert_kernel<<<cblocks, 256, 0, stream>>>(x, w_gate, w_up, w_down, wsg, wsu, wsd,
                                                    xb, wgb, wub, wdb, wsgb, wsub, wsdb);
        ffn1_fast<<<MT_MAX * NT1, 256, 0, stream>>>(xb, wgb, wub, wsgb, wsub, cnt, offs, list, h);
        ffn2_fast<<<MT_MAX * NT2, 256, 0, stream>>>(h, wdb, wsdb, cnt, offs, eo);
        combine_kernel<<<T_TOK, 256, 0, stream>>>(eo, offs, tok_ep, tok_w, out);
    } else {
        bf16* h = (bf16*)(ws + WS_HS);
        hipMemsetAsync(out, 0, (size_t)T_TOK * H_DIM * sizeof(float), stream);
        ffn1_slow<<<MT_MAX * SNT1, 256, 0, stream>>>(x, w_gate, w_up, wsg, wsu, cnt, offs, list, h);
        ffn2_slow<<<MT_MAX * SNT2, 256, 0, stream>>>(h, w_down, wsd, cnt, offs, list, comb, out);
    }
}

// Round 4
// 773.328 us; speedup vs baseline: 1.5830x; 1.0366x over previous
//
#include <hip/hip_runtime.h>
#include <hip/hip_bf16.h>

#define H_DIM 1024
#define I_DIM 2752   // = 43 * 64
#define T_TOK 4096
#define NE 8
#define NROWS (3 * T_TOK)   // 8192 routed pairs + 4096 shared

typedef __bf16 bf16;
typedef __bf16 bf16x8 __attribute__((ext_vector_type(8)));
typedef __bf16 bf16x4 __attribute__((ext_vector_type(4)));
typedef float f32x4 __attribute__((ext_vector_type(4)));

// ---- sizes (elements) ----
constexpr size_t N_X = (size_t)T_TOK * H_DIM;        // 4,194,304
constexpr size_t N_W = (size_t)NE * I_DIM * H_DIM;   // 22,544,384
constexpr size_t N_S = (size_t)I_DIM * H_DIM;        // 2,818,048
constexpr size_t N_H = (size_t)NROWS * I_DIM;        // 33,816,576

// ---- workspace layout (bytes) ----
constexpr size_t WS_CNT  = 0;
constexpr size_t WS_OFFS = 64;
constexpr size_t WS_COMB = 256;                                  // T*NE fp32 (slow path only)
constexpr size_t WS_TOKEP = WS_COMB + (size_t)T_TOK * NE * 4;    // int4 per token
constexpr size_t WS_TOKW  = WS_TOKEP + (size_t)T_TOK * 16;       // float2 per token
constexpr size_t WS_LIST  = WS_TOKW + (size_t)T_TOK * 8;
constexpr size_t WS_XB   = WS_LIST + (size_t)NE * T_TOK * 4;
constexpr size_t WS_WGB  = WS_XB  + N_X * 2;
constexpr size_t WS_WUB  = WS_WGB + N_W * 2;
constexpr size_t WS_WDB  = WS_WUB + N_W * 2;
constexpr size_t WS_WSGB = WS_WDB + N_W * 2;
constexpr size_t WS_WSUB = WS_WSGB + N_S * 2;
constexpr size_t WS_WSDB = WS_WSUB + N_S * 2;
constexpr size_t WS_HF   = WS_WSDB + N_S * 2;
constexpr size_t WS_NEED = WS_HF + N_H * 2;          // ~218 MB
// eo[NROWS][H_DIM] bf16 (24 MB) aliases wgb (45 MB) — wgb is dead after ffn1
constexpr size_t WS_EO   = WS_WGB;
// slow-path h (fallback if ws too small)
constexpr size_t WS_HS   = WS_XB;

// direct global->LDS, 16B per lane. LDS dst is wave-uniform base; HW scatters lane*16.
__device__ inline void gll16(const bf16* g, bf16* l) {
    __builtin_amdgcn_global_load_lds(
        (const __attribute__((address_space(1))) unsigned int*)g,
        (__attribute__((address_space(3))) unsigned int*)l, 16, 0, 0);
}

// ---------------- gating (coalesced; fuses x -> bf16 conversion) ----------------
__global__ void gate_kernel(const float* __restrict__ x, const float* __restrict__ gw,
                            float* __restrict__ comb, int4* __restrict__ tok_ep,
                            float2* __restrict__ tok_w, int* __restrict__ cnt,
                            int* __restrict__ list, bf16* __restrict__ xb) {
    int t = blockIdx.x;
    int lane = threadIdx.x;   // 64
    const float* xr = x + (size_t)t * H_DIM;
    float4 xv[4];
    for (int j = 0; j < 4; ++j) xv[j] = *(const float4*)(xr + lane * 4 + j * 256);
    float p[NE] = {};
    for (int e = 0; e < NE; ++e) {
        const float* wr = gw + (size_t)e * H_DIM;
        for (int j = 0; j < 4; ++j) {
            float4 wv = *(const float4*)(wr + lane * 4 + j * 256);
            p[e] += xv[j].x * wv.x + xv[j].y * wv.y + xv[j].z * wv.z + xv[j].w * wv.w;
        }
    }
    // fused x -> bf16 (fast path input; harmless in slow path)
    for (int j = 0; j < 4; ++j) {
        bf16x4 b = { (bf16)xv[j].x, (bf16)xv[j].y, (bf16)xv[j].z, (bf16)xv[j].w };
        *(bf16x4*)(xb + (size_t)t * H_DIM + lane * 4 + j * 256) = b;
    }
    for (int o = 32; o >= 1; o >>= 1)
        for (int e = 0; e < NE; ++e) p[e] += __shfl_xor(p[e], o);
    if (lane == 0) {
        float m = p[0];
        for (int j = 1; j < NE; ++j) m = fmaxf(m, p[j]);
        float s[NE], Z = 0.f;
        for (int j = 0; j < NE; ++j) { s[j] = expf(p[j] - m); Z += s[j]; }
        for (int j = 0; j < NE; ++j) s[j] /= Z;
        int i0 = 0;
        for (int j = 1; j < NE; ++j) if (s[j] > s[i0]) i0 = j;
        int i1 = (i0 == 0) ? 1 : 0;
        for (int j = 0; j < NE; ++j) if (j != i0 && s[j] > s[i1]) i1 = j;
        float d = s[i0] + s[i1] + 1e-20f;
        float w0 = s[i0] / d, w1 = s[i1] / d;
        for (int j = 0; j < NE; ++j) comb[t * NE + j] = 0.f;
        comb[t * NE + i0] = w0;
        comb[t * NE + i1] = w1;
        int p0 = atomicAdd(&cnt[i0], 1); list[i0 * T_TOK + p0] = t;
        int p1 = atomicAdd(&cnt[i1], 1); list[i1 * T_TOK + p1] = t;
        tok_ep[t] = make_int4(i0, p0, i1, p1);
        tok_w[t] = make_float2(w0, w1);
    }
}

__global__ void offs_kernel(const int* __restrict__ cnt, int* __restrict__ offs) {
    if (threadIdx.x == 0) {
        int a = 0;
        for (int e = 0; e < NE; ++e) { offs[e] = a; a += cnt[e]; }
        offs[NE] = a;   // routed total; shared rows start here
    }
}

// ---------------- fp32 -> bf16 conversion ----------------
__device__ inline void cvt8(const float* __restrict__ s, bf16* __restrict__ d) {
    float4 a = ((const float4*)s)[0];
    float4 b = ((const float4*)s)[1];
    bf16x8 v = { (bf16)a.x, (bf16)a.y, (bf16)a.z, (bf16)a.w,
                 (bf16)b.x, (bf16)b.y, (bf16)b.z, (bf16)b.w };
    *(bf16x8*)d = v;
}

// converts ffn1's weights only (w_down is converted inside ffn1's role blocks)
__global__ void convert_kernel(const float* __restrict__ wg, const float* __restrict__ wu,
                               const float* __restrict__ wsg, const float* __restrict__ wsu,
                               bf16* wgb, bf16* wub, bf16* wsgb, bf16* wsub) {
    size_t i = ((size_t)blockIdx.x * 256 + threadIdx.x) * 8;
    if (i < N_W) { cvt8(wg + i, wgb + i); return; }
    i -= N_W;
    if (i < N_W) { cvt8(wu + i, wub + i); return; }
    i -= N_W;
    if (i < N_S) { cvt8(wsg + i, wsgb + i); return; }
    i -= N_S;
    if (i < N_S) { cvt8(wsu + i, wsub + i); }
}

// map linear m-tile index -> (expert, mtile, count). expert NE == shared.
__device__ inline bool map_tile(const int* cnt, int mt, int bm,
                                int& expert, int& mtile, int& count) {
    for (int e = 0; e <= NE; ++e) {
        int c = (e < NE) ? cnt[e] : T_TOK;
        int tiles = (c + bm - 1) / bm;
        if (mt < tiles) { expert = e; mtile = mt; count = c; return true; }
        mt -= tiles;
    }
    return false;
}

#define BM 128
#define BK 64
#define MT_MAX 104

// ---------------- fast GEMM1: h = silu(x@Wg^T) * (x@Wu^T) ----------------
// leading CONV1_BLKS blocks convert w_down/ws_down to bf16 (overlaps GEMM; ffn2
// needs them only after this kernel completes — kernel boundary is the sync).
#define BN1 64
#define NT1 (I_DIM / BN1)   // 43
#define CONV1_BLKS 3096     // (N_W + N_S) / (256*32) exactly

__global__ __launch_bounds__(256) void ffn1_fast(
    const bf16* __restrict__ xb, const bf16* __restrict__ wgb,
    const bf16* __restrict__ wub, const bf16* __restrict__ wsgb,
    const bf16* __restrict__ wsub, const int* __restrict__ cnt,
    const int* __restrict__ offs, const int* __restrict__ list,
    bf16* __restrict__ h,
    const float* __restrict__ wd_f, const float* __restrict__ wsd_f,
    bf16* __restrict__ wdb, bf16* __restrict__ wsdb) {
    if (blockIdx.x < CONV1_BLKS) {
        size_t base = (size_t)blockIdx.x * 8192 + (size_t)threadIdx.x * 8;
        for (int j = 0; j < 4; ++j) {
            size_t i = base + (size_t)j * 2048;
            if (i < N_W) cvt8(wd_f + i, wdb + i);
            else         cvt8(wsd_f + (i - N_W), wsdb + (i - N_W));
        }
        return;
    }
    int bx = blockIdx.x - CONV1_BLKS;
    int mt = bx % MT_MAX;
    int nt = bx / MT_MAX;
    int expert, mtile, count;
    if (!map_tile(cnt, mt, BM, expert, mtile, count)) return;
    int rowbase = offs[expert];
    const bf16* wg = (expert < NE) ? (wgb + (size_t)expert * N_S) : wsgb;
    const bf16* wu = (expert < NE) ? (wub + (size_t)expert * N_S) : wsub;

    __shared__ bf16 As[BM][BK];
    __shared__ bf16 Bg[BN1][BK];
    __shared__ bf16 Bu[BN1][BK];

    int tid = threadIdx.x;
    int lane = tid & 63, wid = tid >> 6;
    int wm = wid >> 1, wn = wid & 1;
    int lr = lane & 15, lq = lane >> 4;
    int l8 = lane >> 3, c8 = lane & 7;
    int c8s = c8 ^ l8;               // XOR-swizzled source col-group
    int iN = nt * BN1;

    const bf16* aptr[4];
    for (int q = 0; q < 4; ++q) {
        int r = wid * 32 + q * 8 + l8;
        int m = mtile * BM + r;
        int tok = 0;
        if (m < count) tok = (expert < NE) ? list[expert * T_TOK + m] : m;
        aptr[q] = xb + (size_t)tok * H_DIM + c8s * 8;
    }
    const bf16 *gptr[2], *uptr[2];
    for (int q = 0; q < 2; ++q) {
        int r = wid * 16 + q * 8 + l8;
        gptr[q] = wg + (size_t)(iN + r) * H_DIM + c8s * 8;
        uptr[q] = wu + (size_t)(iN + r) * H_DIM + c8s * 8;
    }

    const bf16* Af = &As[0][0];
    const bf16* Bgf = &Bg[0][0];
    const bf16* Buf = &Bu[0][0];

    f32x4 accg[4][2] = {};
    f32x4 accu[4][2] = {};

    for (int kt = 0; kt < H_DIM; kt += BK) {
        for (int q = 0; q < 4; ++q) gll16(aptr[q] + kt, &As[wid * 32 + q * 8][0]);
        for (int q = 0; q < 2; ++q) {
            gll16(gptr[q] + kt, &Bg[wid * 16 + q * 8][0]);
            gll16(uptr[q] + kt, &Bu[wid * 16 + q * 8][0]);
        }
        __syncthreads();
        for (int kk = 0; kk < BK; kk += 32) {
            int G = (kk >> 3) + lq;
            bf16x8 af[4], bg[2], bu[2];
            for (int mi = 0; mi < 4; ++mi) {
                int R = wm * 64 + mi * 16 + lr;
                af[mi] = *(const bf16x8*)(Af + R * 64 + ((G ^ (R & 7)) << 3));
            }
            for (int ni = 0; ni < 2; ++ni) {
                int R = wn * 32 + ni * 16 + lr;
                bg[ni] = *(const bf16x8*)(Bgf + R * 64 + ((G ^ (R & 7)) << 3));
                bu[ni] = *(const bf16x8*)(Buf + R * 64 + ((G ^ (R & 7)) << 3));
            }
            for (int mi = 0; mi < 4; ++mi)
                for (int ni = 0; ni < 2; ++ni) {
                    accg[mi][ni] = __builtin_amdgcn_mfma_f32_16x16x32_bf16(af[mi], bg[ni], accg[mi][ni], 0, 0, 0);
                    accu[mi][ni] = __builtin_amdgcn_mfma_f32_16x16x32_bf16(af[mi], bu[ni], accu[mi][ni], 0, 0, 0);
                }
        }
        __syncthreads();
    }
    for (int mi = 0; mi < 4; ++mi)
        for (int ni = 0; ni < 2; ++ni)
            for (int r2 = 0; r2 < 4; ++r2) {
                int row = wm * 64 + mi * 16 + lq * 4 + r2;
                int m = mtile * BM + row;
                if (m >= count) continue;
                float g = accg[mi][ni][r2], u = accu[mi][ni][r2];
                float hv = g / (1.f + expf(-g)) * u;
                int col = iN + wn * 32 + ni * 16 + lr;
                h[(size_t)(rowbase + m) * I_DIM + col] = (bf16)hv;
            }
}

// ---------------- fast GEMM2: eo = h @ Wd^T (atomic-free, per-row output) ----------------
#define BN2 128
#define NT2 (H_DIM / BN2)   // 8

__global__ __launch_bounds__(256) void ffn2_fast(
    const bf16* __restrict__ h, const bf16* __restrict__ wdb,
    const bf16* __restrict__ wsdb, const int* __restrict__ cnt,
    const int* __restrict__ offs, bf16* __restrict__ eo) {
    int nt = blockIdx.x % NT2;   // nt-fastest: consecutive blocks share the h A-tile
    int mt = blockIdx.x / NT2;
    int expert, mtile, count;
    if (!map_tile(cnt, mt, BM, expert, mtile, count)) return;
    int rowbase = offs[expert];
    const bf16* wd = (expert < NE) ? (wdb + (size_t)expert * N_S) : wsdb;

    __shared__ bf16 As[BM][BK];
    __shared__ bf16 Bs[BN2][BK];

    int tid = threadIdx.x;
    int lane = tid & 63, wid = tid >> 6;
    int wm = wid >> 1, wn = wid & 1;
    int lr = lane & 15, lq = lane >> 4;
    int l8 = lane >> 3, c8 = lane & 7;
    int c8s = c8 ^ l8;
    int hN = nt * BN2;

    const bf16* aptr[4];
    for (int q = 0; q < 4; ++q) {
        int r = wid * 32 + q * 8 + l8;
        int m = mtile * BM + r;
        size_t hrow = (size_t)rowbase + ((m < count) ? m : 0);
        aptr[q] = h + hrow * I_DIM + c8s * 8;
    }
    const bf16* bptr[4];
    for (int q = 0; q < 4; ++q) {
        int r = wid * 32 + q * 8 + l8;
        bptr[q] = wd + (size_t)(hN + r) * I_DIM + c8s * 8;
    }

    const bf16* Af = &As[0][0];
    const bf16* Bf = &Bs[0][0];

    f32x4 acc[4][4] = {};

    for (int kt = 0; kt < I_DIM; kt += BK) {
        for (int q = 0; q < 4; ++q) {
            gll16(aptr[q] + kt, &As[wid * 32 + q * 8][0]);
            gll16(bptr[q] + kt, &Bs[wid * 32 + q * 8][0]);
        }
        __syncthreads();
        for (int kk = 0; kk < BK; kk += 32) {
            int G = (kk >> 3) + lq;
            bf16x8 af[4], bf2[4];
            for (int mi = 0; mi < 4; ++mi) {
                int R = wm * 64 + mi * 16 + lr;
                af[mi] = *(const bf16x8*)(Af + R * 64 + ((G ^ (R & 7)) << 3));
            }
            for (int ni = 0; ni < 4; ++ni) {
                int R = wn * 64 + ni * 16 + lr;
                bf2[ni] = *(const bf16x8*)(Bf + R * 64 + ((G ^ (R & 7)) << 3));
            }
            for (int mi = 0; mi < 4; ++mi)
                for (int ni = 0; ni < 4; ++ni)
                    acc[mi][ni] = __builtin_amdgcn_mfma_f32_16x16x32_bf16(af[mi], bf2[ni], acc[mi][ni], 0, 0, 0);
        }
        __syncthreads();
    }
    for (int mi = 0; mi < 4; ++mi)
        for (int ni = 0; ni < 4; ++ni)
            for (int r2 = 0; r2 < 4; ++r2) {
                int row = wm * 64 + mi * 16 + lq * 4 + r2;
                int m = mtile * BM + row;
                if (m >= count) continue;
                int col = hN + wn * 64 + ni * 16 + lr;
                eo[(size_t)(rowbase + m) * H_DIM + col] = (bf16)acc[mi][ni][r2];
            }
}

// ---------------- combine: out[t] = w0*eo[r0] + w1*eo[r1] + eo[shared_t] ----------------
__global__ __launch_bounds__(256) void combine_kernel(
    const bf16* __restrict__ eo, const int* __restrict__ offs,
    const int4* __restrict__ tok_ep, const float2* __restrict__ tok_w,
    float* __restrict__ out) {
    int t = blockIdx.x;
    int c = threadIdx.x * 4;
    int4 ep = tok_ep[t];
    float2 w = tok_w[t];
    size_t r0 = (size_t)(offs[ep.x] + ep.y) * H_DIM + c;
    size_t r1 = (size_t)(offs[ep.z] + ep.w) * H_DIM + c;
    size_t rs = (size_t)(offs[NE] + t) * H_DIM + c;
    bf16x4 a = *(const bf16x4*)(eo + r0);
    bf16x4 b = *(const bf16x4*)(eo + r1);
    bf16x4 s = *(const bf16x4*)(eo + rs);
    float4 o;
    o.x = w.x * (float)a[0] + w.y * (float)b[0] + (float)s[0];
    o.y = w.x * (float)a[1] + w.y * (float)b[1] + (float)s[1];
    o.z = w.x * (float)a[2] + w.y * (float)b[2] + (float)s[2];
    o.w = w.x * (float)a[3] + w.y * (float)b[3] + (float)s[3];
    *(float4*)(out + (size_t)t * H_DIM + c) = o;
}

// ================= slow fallback (fp32 staging, atomics) =================
#define SBN1 64
#define SNT1 (I_DIM / SBN1)
#define SBN2 64
#define SNT2 (H_DIM / SBN2)

__global__ __launch_bounds__(256) void ffn1_slow(
    const float* __restrict__ x, const float* __restrict__ w_gate,
    const float* __restrict__ w_up, const float* __restrict__ wsg,
    const float* __restrict__ wsu, const int* __restrict__ cnt,
    const int* __restrict__ offs, const int* __restrict__ list,
    bf16* __restrict__ h) {
    int nt = blockIdx.x % SNT1;
    int mt = blockIdx.x / SNT1;
    int expert, mtile, count;
    if (!map_tile(cnt, mt, BM, expert, mtile, count)) return;
    int rowbase = offs[expert];
    const float* wg = (expert < NE) ? (w_gate + (size_t)expert * N_S) : wsg;
    const float* wu = (expert < NE) ? (w_up + (size_t)expert * N_S) : wsu;
    __shared__ bf16 As[BM][BK + 8];
    __shared__ bf16 Bg[SBN1][BK + 8];
    __shared__ bf16 Bu[SBN1][BK + 8];
    int tid = threadIdx.x;
    int lane = tid & 63, wid = tid >> 6;
    int wm = wid >> 1, wn = wid & 1;
    int lr = lane & 15, lq = lane >> 4;
    int cg = tid & 15;
    int iN = nt * SBN1;
    int arow_tok[8];
    for (int p2 = 0; p2 < 8; ++p2) {
        int r = (tid >> 4) + p2 * 16;
        int m = mtile * BM + r;
        arow_tok[p2] = (m < count) ? ((expert < NE) ? list[expert * T_TOK + m] : m) : -1;
    }
    f32x4 accg[4][2] = {};
    f32x4 accu[4][2] = {};
    for (int kt = 0; kt < H_DIM; kt += BK) {
        for (int p2 = 0; p2 < 8; ++p2) {
            int r = (tid >> 4) + p2 * 16;
            int tok = arow_tok[p2];
            float4 v = make_float4(0.f, 0.f, 0.f, 0.f);
            if (tok >= 0) v = *(const float4*)(x + (size_t)tok * H_DIM + kt + cg * 4);
            bf16* dst = &As[r][cg * 4];
            dst[0] = (bf16)v.x; dst[1] = (bf16)v.y; dst[2] = (bf16)v.z; dst[3] = (bf16)v.w;
        }
        for (int p2 = 0; p2 < 4; ++p2) {
            int r = (tid >> 4) + p2 * 16;
            float4 vg = *(const float4*)(wg + (size_t)(iN + r) * H_DIM + kt + cg * 4);
            float4 vu = *(const float4*)(wu + (size_t)(iN + r) * H_DIM + kt + cg * 4);
            bf16* dg = &Bg[r][cg * 4];
            dg[0] = (bf16)vg.x; dg[1] = (bf16)vg.y; dg[2] = (bf16)vg.z; dg[3] = (bf16)vg.w;
            bf16* du = &Bu[r][cg * 4];
            du[0] = (bf16)vu.x; du[1] = (bf16)vu.y; du[2] = (bf16)vu.z; du[3] = (bf16)vu.w;
        }
        __syncthreads();
        for (int kk = 0; kk < BK; kk += 32) {
            bf16x8 af[4], bgf[2], buf2[2];
            for (int mi = 0; mi < 4; ++mi)
                af[mi] = *(const bf16x8*)&As[wm * 64 + mi * 16 + lr][kk + lq * 8];
            for (int ni = 0; ni < 2; ++ni) {
                bgf[ni] = *(const bf16x8*)&Bg[wn * 32 + ni * 16 + lr][kk + lq * 8];
                buf2[ni] = *(const bf16x8*)&Bu[wn * 32 + ni * 16 + lr][kk + lq * 8];
            }
            for (int mi = 0; mi < 4; ++mi)
                for (int ni = 0; ni < 2; ++ni) {
                    accg[mi][ni] = __builtin_amdgcn_mfma_f32_16x16x32_bf16(af[mi], bgf[ni], accg[mi][ni], 0, 0, 0);
                    accu[mi][ni] = __builtin_amdgcn_mfma_f32_16x16x32_bf16(af[mi], buf2[ni], accu[mi][ni], 0, 0, 0);
                }
        }
        __syncthreads();
    }
    for (int mi = 0; mi < 4; ++mi)
        for (int ni = 0; ni < 2; ++ni)
            for (int r2 = 0; r2 < 4; ++r2) {
                int row = wm * 64 + mi * 16 + lq * 4 + r2;
                int m = mtile * BM + row;
                if (m >= count) continue;
                float g = accg[mi][ni][r2], u = accu[mi][ni][r2];
                float hv = g / (1.f + expf(-g)) * u;
                int col = iN + wn * 32 + ni * 16 + lr;
                h[(size_t)(rowbase + m) * I_DIM + col] = (bf16)hv;
            }
}

__global__ __launch_bounds__(256) void ffn2_slow(
    const bf16* __restrict__ h, const float* __restrict__ w_down,
    const float* __restrict__ wsd, const int* __restrict__ cnt,
    const int* __restrict__ offs, const int* __restrict__ list,
    const float* __restrict__ comb, float* __restrict__ out) {
    int nt = blockIdx.x % SNT2;
    int mt = blockIdx.x / SNT2;
    int expert, mtile, count;
    if (!map_tile(cnt, mt, BM, expert, mtile, count)) return;
    int rowbase = offs[expert];
    const float* wd = (expert < NE) ? (w_down + (size_t)expert * N_S) : wsd;
    __shared__ bf16 As[BM][BK + 8];
    __shared__ bf16 Bs[SBN2][BK + 8];
    int tid = threadIdx.x;
    int lane = tid & 63, wid = tid >> 6;
    int wm = wid >> 1, wn = wid & 1;
    int lr = lane & 15, lq = lane >> 4;
    int hN = nt * SBN2;
    int arow_m[4];
    for (int p2 = 0; p2 < 4; ++p2) {
        int r = (tid >> 3) + p2 * 32;
        int m = mtile * BM + r;
        arow_m[p2] = (m < count) ? m : -1;
    }
    f32x4 acc[4][2] = {};
    for (int kt = 0; kt < I_DIM; kt += BK) {
        for (int p2 = 0; p2 < 4; ++p2) {
            int r = (tid >> 3) + p2 * 32;
            int m = arow_m[p2];
            float4 v = make_float4(0.f, 0.f, 0.f, 0.f);
            if (m >= 0) v = *(const float4*)(h + (size_t)(rowbase + m) * I_DIM + kt + (tid & 7) * 8);
            *(float4*)&As[r][(tid & 7) * 8] = v;
        }
        for (int p2 = 0; p2 < 4; ++p2) {
            int r = (tid >> 4) + p2 * 16;
            float4 v = *(const float4*)(wd + (size_t)(hN + r) * I_DIM + kt + (tid & 15) * 4);
            bf16* d = &Bs[r][(tid & 15) * 4];
            d[0] = (bf16)v.x; d[1] = (bf16)v.y; d[2] = (bf16)v.z; d[3] = (bf16)v.w;
        }
        __syncthreads();
        for (int kk = 0; kk < BK; kk += 32) {
            bf16x8 af[4], bf2[2];
            for (int mi = 0; mi < 4; ++mi)
                af[mi] = *(const bf16x8*)&As[wm * 64 + mi * 16 + lr][kk + lq * 8];
            for (int ni = 0; ni < 2; ++ni)
                bf2[ni] = *(const bf16x8*)&Bs[wn * 32 + ni * 16 + lr][kk + lq * 8];
            for (int mi = 0; mi < 4; ++mi)
                for (int ni = 0; ni < 2; ++ni)
                    acc[mi][ni] = __builtin_amdgcn_mfma_f32_16x16x32_bf16(af[mi], bf2[ni], acc[mi][ni], 0, 0, 0);
        }
        __syncthreads();
    }
    for (int mi = 0; mi < 4; ++mi)
        for (int ni = 0; ni < 2; ++ni)
            for (int r2 = 0; r2 < 4; ++r2) {
                int row = wm * 64 + mi * 16 + lq * 4 + r2;
                int m = mtile * BM + row;
                if (m >= count) continue;
                int tok; float wgt;
                if (expert < NE) {
                    tok = list[expert * T_TOK + m];
                    wgt = comb[tok * NE + expert];
                } else {
                    tok = m;
                    wgt = 1.f;
                }
                int col = hN + wn * 32 + ni * 16 + lr;
                atomicAdd(&out[(size_t)tok * H_DIM + col], wgt * acc[mi][ni][r2]);
            }
}

extern "C" void kernel_launch(void* const* d_in, const int* in_sizes, int n_in,
                              void* d_out, int out_size, void* d_ws, size_t ws_size,
                              hipStream_t stream) {
    (void)in_sizes; (void)n_in; (void)out_size;
    const float* x      = (const float*)d_in[0];
    const float* gate_w = (const float*)d_in[1];
    const float* w_gate = (const float*)d_in[2];
    const float* w_up   = (const float*)d_in[3];
    const float* w_down = (const float*)d_in[4];
    const float* wsg    = (const float*)d_in[5];
    const float* wsu    = (const float*)d_in[6];
    const float* wsd    = (const float*)d_in[7];
    float* out = (float*)d_out;
    char* ws = (char*)d_ws;
    int*    cnt    = (int*)(ws + WS_CNT);
    int*    offs   = (int*)(ws + WS_OFFS);
    float*  comb   = (float*)(ws + WS_COMB);
    int4*   tok_ep = (int4*)(ws + WS_TOKEP);
    float2* tok_w  = (float2*)(ws + WS_TOKW);
    int*    list   = (int*)(ws + WS_LIST);
    bf16*   xb     = (bf16*)(ws + WS_XB);

    hipMemsetAsync(cnt, 0, 64, stream);
    gate_kernel<<<T_TOK, 64, 0, stream>>>(x, gate_w, comb, tok_ep, tok_w, cnt, list, xb);
    offs_kernel<<<1, 64, 0, stream>>>(cnt, offs);

    if (ws_size >= WS_NEED) {
        bf16* wgb  = (bf16*)(ws + WS_WGB);
        bf16* wub  = (bf16*)(ws + WS_WUB);
        bf16* wdb  = (bf16*)(ws + WS_WDB);
        bf16* wsgb = (bf16*)(ws + WS_WSGB);
        bf16* wsub = (bf16*)(ws + WS_WSUB);
        bf16* wsdb = (bf16*)(ws + WS_WSDB);
        bf16* h    = (bf16*)(ws + WS_HF);
        bf16* eo   = (bf16*)(ws + WS_EO);    // aliases wgb (dead after ffn1)
        size_t total8 = (2 * N_W + 2 * N_S) / 8;     // wg, wu, wsg, wsu
        int cblocks = (int)((total8 + 255) / 256);   // 24768
        convert_kernel<<<cblocks, 256, 0, stream>>>(w_gate, w_up, wsg, wsu,
                                                    wgb, wub, wsgb, wsub);
        ffn1_fast<<<CONV1_BLKS + MT_MAX * NT1, 256, 0, stream>>>(
            xb, wgb, wub, wsgb, wsub, cnt, offs, list, h,
            w_down, wsd, wdb, wsdb);
        ffn2_fast<<<MT_MAX * NT2, 256, 0, stream>>>(h, wdb, wsdb, cnt, offs, eo);
        combine_kernel<<<T_TOK, 256, 0, stream>>>(eo, offs, tok_ep, tok_w, out);
    } else {
        bf16* h = (bf16*)(ws + WS_HS);
        hipMemsetAsync(out, 0, (size_t)T_TOK * H_DIM * sizeof(float), stream);
        ffn1_slow<<<MT_MAX * SNT1, 256, 0, stream>>>(x, w_gate, w_up, wsg, wsu, cnt, offs, list, h);
        ffn2_slow<<<MT_MAX * SNT2, 256, 0, stream>>>(h, w_down, wsd, cnt, offs, list, comb, out);
    }
}

// Round 5
// 747.604 us; speedup vs baseline: 1.6375x; 1.0344x over previous
//
#include <hip/hip_runtime.h>
#include <hip/hip_bf16.h>

#define H_DIM 1024
#define I_DIM 2752   // = 43 * 64
#define T_TOK 4096
#define NE 8
#define NROWS (3 * T_TOK)   // 8192 routed pairs + 4096 shared

typedef __bf16 bf16;
typedef __bf16 bf16x8 __attribute__((ext_vector_type(8)));
typedef __bf16 bf16x4 __attribute__((ext_vector_type(4)));
typedef float f32x4 __attribute__((ext_vector_type(4)));

// ---- sizes (elements) ----
constexpr size_t N_X = (size_t)T_TOK * H_DIM;        // 4,194,304
constexpr size_t N_W = (size_t)NE * I_DIM * H_DIM;   // 22,544,384
constexpr size_t N_S = (size_t)I_DIM * H_DIM;        // 2,818,048
constexpr size_t N_H = (size_t)NROWS * I_DIM;        // 33,816,576

// ---- workspace layout (bytes) ----
constexpr size_t WS_CNT  = 0;
constexpr size_t WS_OFFS = 64;
constexpr size_t WS_COMB = 256;                                  // T*NE fp32 (slow path only)
constexpr size_t WS_TOKEP = WS_COMB + (size_t)T_TOK * NE * 4;    // int4 per token
constexpr size_t WS_TOKW  = WS_TOKEP + (size_t)T_TOK * 16;       // float2 per token
constexpr size_t WS_LIST  = WS_TOKW + (size_t)T_TOK * 8;
constexpr size_t WS_XB   = WS_LIST + (size_t)NE * T_TOK * 4;
constexpr size_t WS_WGB  = WS_XB  + N_X * 2;
constexpr size_t WS_WUB  = WS_WGB + N_W * 2;
constexpr size_t WS_WDB  = WS_WUB + N_W * 2;
constexpr size_t WS_WSGB = WS_WDB + N_W * 2;
constexpr size_t WS_WSUB = WS_WSGB + N_S * 2;
constexpr size_t WS_WSDB = WS_WSUB + N_S * 2;
constexpr size_t WS_HF   = WS_WSDB + N_S * 2;
constexpr size_t WS_NEED = WS_HF + N_H * 2;          // ~218 MB
// eo[NROWS][H_DIM] bf16 (24 MB) aliases wgb (45 MB) — wgb is dead after ffn1
constexpr size_t WS_EO   = WS_WGB;
// slow-path h (fallback if ws too small)
constexpr size_t WS_HS   = WS_XB;

// direct global->LDS, 16B per lane. LDS dst is wave-uniform base; HW scatters lane*16.
__device__ inline void gll16(const bf16* g, bf16* l) {
    __builtin_amdgcn_global_load_lds(
        (const __attribute__((address_space(1))) unsigned int*)g,
        (__attribute__((address_space(3))) unsigned int*)l, 16, 0, 0);
}

// ---------------- gating (coalesced; fuses x -> bf16 conversion) ----------------
__global__ void gate_kernel(const float* __restrict__ x, const float* __restrict__ gw,
                            float* __restrict__ comb, int4* __restrict__ tok_ep,
                            float2* __restrict__ tok_w, int* __restrict__ cnt,
                            int* __restrict__ list, bf16* __restrict__ xb) {
    int t = blockIdx.x;
    int lane = threadIdx.x;   // 64
    const float* xr = x + (size_t)t * H_DIM;
    float4 xv[4];
    for (int j = 0; j < 4; ++j) xv[j] = *(const float4*)(xr + lane * 4 + j * 256);
    float p[NE] = {};
    for (int e = 0; e < NE; ++e) {
        const float* wr = gw + (size_t)e * H_DIM;
        for (int j = 0; j < 4; ++j) {
            float4 wv = *(const float4*)(wr + lane * 4 + j * 256);
            p[e] += xv[j].x * wv.x + xv[j].y * wv.y + xv[j].z * wv.z + xv[j].w * wv.w;
        }
    }
    for (int j = 0; j < 4; ++j) {
        bf16x4 b = { (bf16)xv[j].x, (bf16)xv[j].y, (bf16)xv[j].z, (bf16)xv[j].w };
        *(bf16x4*)(xb + (size_t)t * H_DIM + lane * 4 + j * 256) = b;
    }
    for (int o = 32; o >= 1; o >>= 1)
        for (int e = 0; e < NE; ++e) p[e] += __shfl_xor(p[e], o);
    if (lane == 0) {
        float m = p[0];
        for (int j = 1; j < NE; ++j) m = fmaxf(m, p[j]);
        float s[NE], Z = 0.f;
        for (int j = 0; j < NE; ++j) { s[j] = expf(p[j] - m); Z += s[j]; }
        for (int j = 0; j < NE; ++j) s[j] /= Z;
        int i0 = 0;
        for (int j = 1; j < NE; ++j) if (s[j] > s[i0]) i0 = j;
        int i1 = (i0 == 0) ? 1 : 0;
        for (int j = 0; j < NE; ++j) if (j != i0 && s[j] > s[i1]) i1 = j;
        float d = s[i0] + s[i1] + 1e-20f;
        float w0 = s[i0] / d, w1 = s[i1] / d;
        for (int j = 0; j < NE; ++j) comb[t * NE + j] = 0.f;
        comb[t * NE + i0] = w0;
        comb[t * NE + i1] = w1;
        int p0 = atomicAdd(&cnt[i0], 1); list[i0 * T_TOK + p0] = t;
        int p1 = atomicAdd(&cnt[i1], 1); list[i1 * T_TOK + p1] = t;
        tok_ep[t] = make_int4(i0, p0, i1, p1);
        tok_w[t] = make_float2(w0, w1);
    }
}

__global__ void offs_kernel(const int* __restrict__ cnt, int* __restrict__ offs) {
    if (threadIdx.x == 0) {
        int a = 0;
        for (int e = 0; e < NE; ++e) { offs[e] = a; a += cnt[e]; }
        offs[NE] = a;   // routed total; shared rows start here
    }
}

// ---------------- fp32 -> bf16 conversion ----------------
__device__ inline void cvt8(const float* __restrict__ s, bf16* __restrict__ d) {
    float4 a = ((const float4*)s)[0];
    float4 b = ((const float4*)s)[1];
    bf16x8 v = { (bf16)a.x, (bf16)a.y, (bf16)a.z, (bf16)a.w,
                 (bf16)b.x, (bf16)b.y, (bf16)b.z, (bf16)b.w };
    *(bf16x8*)d = v;
}

// converts ffn1's weights only (w_down converted inside ffn1's role blocks)
__global__ void convert_kernel(const float* __restrict__ wg, const float* __restrict__ wu,
                               const float* __restrict__ wsg, const float* __restrict__ wsu,
                               bf16* wgb, bf16* wub, bf16* wsgb, bf16* wsub) {
    size_t i = ((size_t)blockIdx.x * 256 + threadIdx.x) * 8;
    if (i < N_W) { cvt8(wg + i, wgb + i); return; }
    i -= N_W;
    if (i < N_W) { cvt8(wu + i, wub + i); return; }
    i -= N_W;
    if (i < N_S) { cvt8(wsg + i, wsgb + i); return; }
    i -= N_S;
    if (i < N_S) { cvt8(wsu + i, wsub + i); }
}

#define BM 128
#define MT_MAX 104
#define BK 64

// supertile map: expert-major; within expert, groups of 8 m-tiles x nt_cnt n-tiles,
// msub fastest (8 consecutive blocks share a B n-tile; a group of 8*nt_cnt blocks
// touches only an 8-m-tile A-slab + nt_cnt B-tiles -> L2-friendly window).
__device__ inline bool map_super(const int* cnt, int bx, int nt_cnt,
                                 int& expert, int& mtile, int& nt, int& count) {
    for (int e = 0; e <= NE; ++e) {
        int c = (e < NE) ? cnt[e] : T_TOK;
        int tiles = (c + BM - 1) / BM;
        int blocks = tiles * nt_cnt;
        if (bx < blocks) {
            int full = tiles & ~7;              // m-tiles in full groups of 8
            int fullblocks = full * nt_cnt;
            int mg0, gsz, rem;
            if (bx < fullblocks) { mg0 = (bx / (nt_cnt * 8)) * 8; gsz = 8; rem = bx % (nt_cnt * 8); }
            else                 { mg0 = full; gsz = tiles - full; rem = bx - fullblocks; }
            nt = rem / gsz;
            mtile = mg0 + rem % gsz;
            expert = e; count = c;
            return true;
        }
        bx -= blocks;
    }
    return false;
}

// linear map (slow path)
__device__ inline bool map_tile(const int* cnt, int mt, int bm,
                                int& expert, int& mtile, int& count) {
    for (int e = 0; e <= NE; ++e) {
        int c = (e < NE) ? cnt[e] : T_TOK;
        int tiles = (c + bm - 1) / bm;
        if (mt < tiles) { expert = e; mtile = mt; count = c; return true; }
        mt -= tiles;
    }
    return false;
}

// ---------------- fast GEMM1: h = silu(x@Wg^T) * (x@Wu^T) ----------------
#define BN1 64
#define NT1 (I_DIM / BN1)   // 43
#define CONV1_BLKS 3096     // (N_W + N_S) / (256*32) exactly

__global__ __launch_bounds__(256) void ffn1_fast(
    const bf16* __restrict__ xb, const bf16* __restrict__ wgb,
    const bf16* __restrict__ wub, const bf16* __restrict__ wsgb,
    const bf16* __restrict__ wsub, const int* __restrict__ cnt,
    const int* __restrict__ offs, const int* __restrict__ list,
    bf16* __restrict__ h,
    const float* __restrict__ wd_f, const float* __restrict__ wsd_f,
    bf16* __restrict__ wdb, bf16* __restrict__ wsdb) {
    if (blockIdx.x < CONV1_BLKS) {
        size_t base = (size_t)blockIdx.x * 8192 + (size_t)threadIdx.x * 8;
        for (int j = 0; j < 4; ++j) {
            size_t i = base + (size_t)j * 2048;
            if (i < N_W) cvt8(wd_f + i, wdb + i);
            else         cvt8(wsd_f + (i - N_W), wsdb + (i - N_W));
        }
        return;
    }
    int bx = blockIdx.x - CONV1_BLKS;
    int expert, mtile, nt, count;
    if (!map_super(cnt, bx, NT1, expert, mtile, nt, count)) return;
    int rowbase = offs[expert];
    const bf16* wg = (expert < NE) ? (wgb + (size_t)expert * N_S) : wsgb;
    const bf16* wu = (expert < NE) ? (wub + (size_t)expert * N_S) : wsub;

    __shared__ bf16 As[BM][BK];
    __shared__ bf16 Bg[BN1][BK];
    __shared__ bf16 Bu[BN1][BK];

    int tid = threadIdx.x;
    int lane = tid & 63, wid = tid >> 6;
    int wm = wid >> 1, wn = wid & 1;
    int lr = lane & 15, lq = lane >> 4;
    int l8 = lane >> 3, c8 = lane & 7;
    int c8s = c8 ^ l8;               // XOR-swizzled source col-group
    int iN = nt * BN1;

    const bf16* aptr[4];
    for (int q = 0; q < 4; ++q) {
        int r = wid * 32 + q * 8 + l8;
        int m = mtile * BM + r;
        int tok = 0;
        if (m < count) tok = (expert < NE) ? list[expert * T_TOK + m] : m;
        aptr[q] = xb + (size_t)tok * H_DIM + c8s * 8;
    }
    const bf16 *gptr[2], *uptr[2];
    for (int q = 0; q < 2; ++q) {
        int r = wid * 16 + q * 8 + l8;
        gptr[q] = wg + (size_t)(iN + r) * H_DIM + c8s * 8;
        uptr[q] = wu + (size_t)(iN + r) * H_DIM + c8s * 8;
    }

    const bf16* Af = &As[0][0];
    const bf16* Bgf = &Bg[0][0];
    const bf16* Buf = &Bu[0][0];

    f32x4 accg[4][2] = {};
    f32x4 accu[4][2] = {};

    for (int kt = 0; kt < H_DIM; kt += BK) {
        for (int q = 0; q < 4; ++q) gll16(aptr[q] + kt, &As[wid * 32 + q * 8][0]);
        for (int q = 0; q < 2; ++q) {
            gll16(gptr[q] + kt, &Bg[wid * 16 + q * 8][0]);
            gll16(uptr[q] + kt, &Bu[wid * 16 + q * 8][0]);
        }
        __syncthreads();
        for (int kk = 0; kk < BK; kk += 32) {
            int G = (kk >> 3) + lq;
            bf16x8 af[4], bg[2], bu[2];
            for (int mi = 0; mi < 4; ++mi) {
                int R = wm * 64 + mi * 16 + lr;
                af[mi] = *(const bf16x8*)(Af + R * 64 + ((G ^ (R & 7)) << 3));
            }
            for (int ni = 0; ni < 2; ++ni) {
                int R = wn * 32 + ni * 16 + lr;
                bg[ni] = *(const bf16x8*)(Bgf + R * 64 + ((G ^ (R & 7)) << 3));
                bu[ni] = *(const bf16x8*)(Buf + R * 64 + ((G ^ (R & 7)) << 3));
            }
            for (int mi = 0; mi < 4; ++mi)
                for (int ni = 0; ni < 2; ++ni) {
                    accg[mi][ni] = __builtin_amdgcn_mfma_f32_16x16x32_bf16(af[mi], bg[ni], accg[mi][ni], 0, 0, 0);
                    accu[mi][ni] = __builtin_amdgcn_mfma_f32_16x16x32_bf16(af[mi], bu[ni], accu[mi][ni], 0, 0, 0);
                }
        }
        __syncthreads();
    }
    for (int mi = 0; mi < 4; ++mi)
        for (int ni = 0; ni < 2; ++ni)
            for (int r2 = 0; r2 < 4; ++r2) {
                int row = wm * 64 + mi * 16 + lq * 4 + r2;
                int m = mtile * BM + row;
                if (m >= count) continue;
                float g = accg[mi][ni][r2], u = accu[mi][ni][r2];
                float hv = g / (1.f + expf(-g)) * u;
                int col = iN + wn * 32 + ni * 16 + lr;
                h[(size_t)(rowbase + m) * I_DIM + col] = (bf16)hv;
            }
}

// ---------------- fast GEMM2: eo = h @ Wd^T, 128x64 tiles, supertiled ----------------
#define BN2 64
#define NT2 (H_DIM / BN2)   // 16

__global__ __launch_bounds__(256) void ffn2_fast(
    const bf16* __restrict__ h, const bf16* __restrict__ wdb,
    const bf16* __restrict__ wsdb, const int* __restrict__ cnt,
    const int* __restrict__ offs, bf16* __restrict__ eo) {
    int expert, mtile, nt, count;
    if (!map_super(cnt, blockIdx.x, NT2, expert, mtile, nt, count)) return;
    int rowbase = offs[expert];
    const bf16* wd = (expert < NE) ? (wdb + (size_t)expert * N_S) : wsdb;

    __shared__ bf16 As[BM][BK];    // 16 KB
    __shared__ bf16 Bs[BN2][BK];   // 8 KB

    int tid = threadIdx.x;
    int lane = tid & 63, wid = tid >> 6;
    int wm = wid >> 1, wn = wid & 1;
    int lr = lane & 15, lq = lane >> 4;
    int l8 = lane >> 3, c8 = lane & 7;
    int c8s = c8 ^ l8;
    int hN = nt * BN2;

    const bf16* aptr[4];
    for (int q = 0; q < 4; ++q) {
        int r = wid * 32 + q * 8 + l8;
        int m = mtile * BM + r;
        size_t hrow = (size_t)rowbase + ((m < count) ? m : 0);
        aptr[q] = h + hrow * I_DIM + c8s * 8;
    }
    const bf16* bptr[2];
    for (int q = 0; q < 2; ++q) {
        int r = wid * 16 + q * 8 + l8;
        bptr[q] = wd + (size_t)(hN + r) * I_DIM + c8s * 8;
    }

    const bf16* Af = &As[0][0];
    const bf16* Bf = &Bs[0][0];

    f32x4 acc[4][2] = {};

    for (int kt = 0; kt < I_DIM; kt += BK) {
        for (int q = 0; q < 4; ++q) gll16(aptr[q] + kt, &As[wid * 32 + q * 8][0]);
        for (int q = 0; q < 2; ++q) gll16(bptr[q] + kt, &Bs[wid * 16 + q * 8][0]);
        __syncthreads();
        for (int kk = 0; kk < BK; kk += 32) {
            int G = (kk >> 3) + lq;
            bf16x8 af[4], bf2[2];
            for (int mi = 0; mi < 4; ++mi) {
                int R = wm * 64 + mi * 16 + lr;
                af[mi] = *(const bf16x8*)(Af + R * 64 + ((G ^ (R & 7)) << 3));
            }
            for (int ni = 0; ni < 2; ++ni) {
                int R = wn * 32 + ni * 16 + lr;
                bf2[ni] = *(const bf16x8*)(Bf + R * 64 + ((G ^ (R & 7)) << 3));
            }
            for (int mi = 0; mi < 4; ++mi)
                for (int ni = 0; ni < 2; ++ni)
                    acc[mi][ni] = __builtin_amdgcn_mfma_f32_16x16x32_bf16(af[mi], bf2[ni], acc[mi][ni], 0, 0, 0);
        }
        __syncthreads();
    }
    for (int mi = 0; mi < 4; ++mi)
        for (int ni = 0; ni < 2; ++ni)
            for (int r2 = 0; r2 < 4; ++r2) {
                int row = wm * 64 + mi * 16 + lq * 4 + r2;
                int m = mtile * BM + row;
                if (m >= count) continue;
                int col = hN + wn * 32 + ni * 16 + lr;
                eo[(size_t)(rowbase + m) * H_DIM + col] = (bf16)acc[mi][ni][r2];
            }
}

// ---------------- combine: out[t] = w0*eo[r0] + w1*eo[r1] + eo[shared_t] ----------------
__global__ __launch_bounds__(256) void combine_kernel(
    const bf16* __restrict__ eo, const int* __restrict__ offs,
    const int4* __restrict__ tok_ep, const float2* __restrict__ tok_w,
    float* __restrict__ out) {
    int t = blockIdx.x;
    int c = threadIdx.x * 4;
    int4 ep = tok_ep[t];
    float2 w = tok_w[t];
    size_t r0 = (size_t)(offs[ep.x] + ep.y) * H_DIM + c;
    size_t r1 = (size_t)(offs[ep.z] + ep.w) * H_DIM + c;
    size_t rs = (size_t)(offs[NE] + t) * H_DIM + c;
    bf16x4 a = *(const bf16x4*)(eo + r0);
    bf16x4 b = *(const bf16x4*)(eo + r1);
    bf16x4 s = *(const bf16x4*)(eo + rs);
    float4 o;
    o.x = w.x * (float)a[0] + w.y * (float)b[0] + (float)s[0];
    o.y = w.x * (float)a[1] + w.y * (float)b[1] + (float)s[1];
    o.z = w.x * (float)a[2] + w.y * (float)b[2] + (float)s[2];
    o.w = w.x * (float)a[3] + w.y * (float)b[3] + (float)s[3];
    *(float4*)(out + (size_t)t * H_DIM + c) = o;
}

// ================= slow fallback (fp32 staging, atomics) =================
#define SBN1 64
#define SNT1 (I_DIM / SBN1)
#define SBN2 64
#define SNT2 (H_DIM / SBN2)

__global__ __launch_bounds__(256) void ffn1_slow(
    const float* __restrict__ x, const float* __restrict__ w_gate,
    const float* __restrict__ w_up, const float* __restrict__ wsg,
    const float* __restrict__ wsu, const int* __restrict__ cnt,
    const int* __restrict__ offs, const int* __restrict__ list,
    bf16* __restrict__ h) {
    int nt = blockIdx.x % SNT1;
    int mt = blockIdx.x / SNT1;
    int expert, mtile, count;
    if (!map_tile(cnt, mt, BM, expert, mtile, count)) return;
    int rowbase = offs[expert];
    const float* wg = (expert < NE) ? (w_gate + (size_t)expert * N_S) : wsg;
    const float* wu = (expert < NE) ? (w_up + (size_t)expert * N_S) : wsu;
    __shared__ bf16 As[BM][BK + 8];
    __shared__ bf16 Bg[SBN1][BK + 8];
    __shared__ bf16 Bu[SBN1][BK + 8];
    int tid = threadIdx.x;
    int lane = tid & 63, wid = tid >> 6;
    int wm = wid >> 1, wn = wid & 1;
    int lr = lane & 15, lq = lane >> 4;
    int cg = tid & 15;
    int iN = nt * SBN1;
    int arow_tok[8];
    for (int p2 = 0; p2 < 8; ++p2) {
        int r = (tid >> 4) + p2 * 16;
        int m = mtile * BM + r;
        arow_tok[p2] = (m < count) ? ((expert < NE) ? list[expert * T_TOK + m] : m) : -1;
    }
    f32x4 accg[4][2] = {};
    f32x4 accu[4][2] = {};
    for (int kt = 0; kt < H_DIM; kt += BK) {
        for (int p2 = 0; p2 < 8; ++p2) {
            int r = (tid >> 4) + p2 * 16;
            int tok = arow_tok[p2];
            float4 v = make_float4(0.f, 0.f, 0.f, 0.f);
            if (tok >= 0) v = *(const float4*)(x + (size_t)tok * H_DIM + kt + cg * 4);
            bf16* dst = &As[r][cg * 4];
            dst[0] = (bf16)v.x; dst[1] = (bf16)v.y; dst[2] = (bf16)v.z; dst[3] = (bf16)v.w;
        }
        for (int p2 = 0; p2 < 4; ++p2) {
            int r = (tid >> 4) + p2 * 16;
            float4 vg = *(const float4*)(wg + (size_t)(iN + r) * H_DIM + kt + cg * 4);
            float4 vu = *(const float4*)(wu + (size_t)(iN + r) * H_DIM + kt + cg * 4);
            bf16* dg = &Bg[r][cg * 4];
            dg[0] = (bf16)vg.x; dg[1] = (bf16)vg.y; dg[2] = (bf16)vg.z; dg[3] = (bf16)vg.w;
            bf16* du = &Bu[r][cg * 4];
            du[0] = (bf16)vu.x; du[1] = (bf16)vu.y; du[2] = (bf16)vu.z; du[3] = (bf16)vu.w;
        }
        __syncthreads();
        for (int kk = 0; kk < BK; kk += 32) {
            bf16x8 af[4], bgf[2], buf2[2];
            for (int mi = 0; mi < 4; ++mi)
                af[mi] = *(const bf16x8*)&As[wm * 64 + mi * 16 + lr][kk + lq * 8];
            for (int ni = 0; ni < 2; ++ni) {
                bgf[ni] = *(const bf16x8*)&Bg[wn * 32 + ni * 16 + lr][kk + lq * 8];
                buf2[ni] = *(const bf16x8*)&Bu[wn * 32 + ni * 16 + lr][kk + lq * 8];
            }
            for (int mi = 0; mi < 4; ++mi)
                for (int ni = 0; ni < 2; ++ni) {
                    accg[mi][ni] = __builtin_amdgcn_mfma_f32_16x16x32_bf16(af[mi], bgf[ni], accg[mi][ni], 0, 0, 0);
                    accu[mi][ni] = __builtin_amdgcn_mfma_f32_16x16x32_bf16(af[mi], buf2[ni], accu[mi][ni], 0, 0, 0);
                }
        }
        __syncthreads();
    }
    for (int mi = 0; mi < 4; ++mi)
        for (int ni = 0; ni < 2; ++ni)
            for (int r2 = 0; r2 < 4; ++r2) {
                int row = wm * 64 + mi * 16 + lq * 4 + r2;
                int m = mtile * BM + row;
                if (m >= count) continue;
                float g = accg[mi][ni][r2], u = accu[mi][ni][r2];
                float hv = g / (1.f + expf(-g)) * u;
                int col = iN + wn * 32 + ni * 16 + lr;
                h[(size_t)(rowbase + m) * I_DIM + col] = (bf16)hv;
            }
}

__global__ __launch_bounds__(256) void ffn2_slow(
    const bf16* __restrict__ h, const float* __restrict__ w_down,
    const float* __restrict__ wsd, const int* __restrict__ cnt,
    const int* __restrict__ offs, const int* __restrict__ list,
    const float* __restrict__ comb, float* __restrict__ out) {
    int nt = blockIdx.x % SNT2;
    int mt = blockIdx.x / SNT2;
    int expert, mtile, count;
    if (!map_tile(cnt, mt, BM, expert, mtile, count)) return;
    int rowbase = offs[expert];
    const float* wd = (expert < NE) ? (w_down + (size_t)expert * N_S) : wsd;
    __shared__ bf16 As[BM][BK + 8];
    __shared__ bf16 Bs[SBN2][BK + 8];
    int tid = threadIdx.x;
    int lane = tid & 63, wid = tid >> 6;
    int wm = wid >> 1, wn = wid & 1;
    int lr = lane & 15, lq = lane >> 4;
    int hN = nt * SBN2;
    int arow_m[4];
    for (int p2 = 0; p2 < 4; ++p2) {
        int r = (tid >> 3) + p2 * 32;
        int m = mtile * BM + r;
        arow_m[p2] = (m < count) ? m : -1;
    }
    f32x4 acc[4][2] = {};
    for (int kt = 0; kt < I_DIM; kt += BK) {
        for (int p2 = 0; p2 < 4; ++p2) {
            int r = (tid >> 3) + p2 * 32;
            int m = arow_m[p2];
            float4 v = make_float4(0.f, 0.f, 0.f, 0.f);
            if (m >= 0) v = *(const float4*)(h + (size_t)(rowbase + m) * I_DIM + kt + (tid & 7) * 8);
            *(float4*)&As[r][(tid & 7) * 8] = v;
        }
        for (int p2 = 0; p2 < 4; ++p2) {
            int r = (tid >> 4) + p2 * 16;
            float4 v = *(const float4*)(wd + (size_t)(hN + r) * I_DIM + kt + (tid & 15) * 4);
            bf16* d = &Bs[r][(tid & 15) * 4];
            d[0] = (bf16)v.x; d[1] = (bf16)v.y; d[2] = (bf16)v.z; d[3] = (bf16)v.w;
        }
        __syncthreads();
        for (int kk = 0; kk < BK; kk += 32) {
            bf16x8 af[4], bf2[2];
            for (int mi = 0; mi < 4; ++mi)
                af[mi] = *(const bf16x8*)&As[wm * 64 + mi * 16 + lr][kk + lq * 8];
            for (int ni = 0; ni < 2; ++ni)
                bf2[ni] = *(const bf16x8*)&Bs[wn * 32 + ni * 16 + lr][kk + lq * 8];
            for (int mi = 0; mi < 4; ++mi)
                for (int ni = 0; ni < 2; ++ni)
                    acc[mi][ni] = __builtin_amdgcn_mfma_f32_16x16x32_bf16(af[mi], bf2[ni], acc[mi][ni], 0, 0, 0);
        }
        __syncthreads();
    }
    for (int mi = 0; mi < 4; ++mi)
        for (int ni = 0; ni < 2; ++ni)
            for (int r2 = 0; r2 < 4; ++r2) {
                int row = wm * 64 + mi * 16 + lq * 4 + r2;
                int m = mtile * BM + row;
                if (m >= count) continue;
                int tok; float wgt;
                if (expert < NE) {
                    tok = list[expert * T_TOK + m];
                    wgt = comb[tok * NE + expert];
                } else {
                    tok = m;
                    wgt = 1.f;
                }
                int col = hN + wn * 32 + ni * 16 + lr;
                atomicAdd(&out[(size_t)tok * H_DIM + col], wgt * acc[mi][ni][r2]);
            }
}

extern "C" void kernel_launch(void* const* d_in, const int* in_sizes, int n_in,
                              void* d_out, int out_size, void* d_ws, size_t ws_size,
                              hipStream_t stream) {
    (void)in_sizes; (void)n_in; (void)out_size;
    const float* x      = (const float*)d_in[0];
    const float* gate_w = (const float*)d_in[1];
    const float* w_gate = (const float*)d_in[2];
    const float* w_up   = (const float*)d_in[3];
    const float* w_down = (const float*)d_in[4];
    const float* wsg    = (const float*)d_in[5];
    const float* wsu    = (const float*)d_in[6];
    const float* wsd    = (const float*)d_in[7];
    float* out = (float*)d_out;
    char* ws = (char*)d_ws;
    int*    cnt    = (int*)(ws + WS_CNT);
    int*    offs   = (int*)(ws + WS_OFFS);
    float*  comb   = (float*)(ws + WS_COMB);
    int4*   tok_ep = (int4*)(ws + WS_TOKEP);
    float2* tok_w  = (float2*)(ws + WS_TOKW);
    int*    list   = (int*)(ws + WS_LIST);
    bf16*   xb     = (bf16*)(ws + WS_XB);

    hipMemsetAsync(cnt, 0, 64, stream);
    gate_kernel<<<T_TOK, 64, 0, stream>>>(x, gate_w, comb, tok_ep, tok_w, cnt, list, xb);
    offs_kernel<<<1, 64, 0, stream>>>(cnt, offs);

    if (ws_size >= WS_NEED) {
        bf16* wgb  = (bf16*)(ws + WS_WGB);
        bf16* wub  = (bf16*)(ws + WS_WUB);
        bf16* wdb  = (bf16*)(ws + WS_WDB);
        bf16* wsgb = (bf16*)(ws + WS_WSGB);
        bf16* wsub = (bf16*)(ws + WS_WSUB);
        bf16* wsdb = (bf16*)(ws + WS_WSDB);
        bf16* h    = (bf16*)(ws + WS_HF);
        bf16* eo   = (bf16*)(ws + WS_EO);    // aliases wgb (dead after ffn1)
        size_t total8 = (2 * N_W + 2 * N_S) / 8;     // wg, wu, wsg, wsu
        int cblocks = (int)((total8 + 255) / 256);   // 24768
        convert_kernel<<<cblocks, 256, 0, stream>>>(w_gate, w_up, wsg, wsu,
                                                    wgb, wub, wsgb, wsub);
        ffn1_fast<<<CONV1_BLKS + MT_MAX * NT1, 256, 0, stream>>>(
            xb, wgb, wub, wsgb, wsub, cnt, offs, list, h,
            w_down, wsd, wdb, wsdb);
        ffn2_fast<<<MT_MAX * NT2, 256, 0, stream>>>(h, wdb, wsdb, cnt, offs, eo);
        combine_kernel<<<T_TOK, 256, 0, stream>>>(eo, offs, tok_ep, tok_w, out);
    } else {
        bf16* h = (bf16*)(ws + WS_HS);
        hipMemsetAsync(out, 0, (size_t)T_TOK * H_DIM * sizeof(float), stream);
        ffn1_slow<<<MT_MAX * SNT1, 256, 0, stream>>>(x, w_gate, w_up, wsg, wsu, cnt, offs, list, h);
        ffn2_slow<<<MT_MAX * SNT2, 256, 0, stream>>>(h, w_down, wsd, cnt, offs, list, comb, out);
    }
}